// Round 1
// baseline (4412.742 us; speedup 1.0000x reference)
//
#include <hip/hip_runtime.h>
#include <hip/hip_bf16.h>

// MLA forward, fp32 baseline.
// Stages: QKV GEMMs -> RoPE -> latent compression GEMMs -> flash attention
//         (latent dim 64) -> decompression GEMM -> output GEMM.

static constexpr int Bsz = 2;
static constexpr int Tn  = 2048;
static constexpr int Dn  = 2048;
static constexpr int Hn  = 16;
static constexpr int Ln  = 64;
static constexpr int Hd  = 128;
static constexpr float SCALE = 0.125f;  // 1/sqrt(64)

// ---------------- generic fp32 tiled GEMM: C = A[M,K] @ B[K,N] + bias[N] ----
static constexpr int TS = 64;   // output tile 64x64
static constexpr int KT = 16;   // K-step

__global__ __launch_bounds__(256) void gemm_f32(const float* __restrict__ A,
                                                const float* __restrict__ Bm,
                                                const float* __restrict__ bias,
                                                float* __restrict__ C,
                                                int M, int N, int K) {
  __shared__ float As[KT][TS + 4];
  __shared__ float Bs[KT][TS + 4];
  const int tid = threadIdx.x;
  const int tx = tid & 15, ty = tid >> 4;
  const int row0 = blockIdx.y * TS, col0 = blockIdx.x * TS;
  float acc[4][4] = {};
  for (int k0 = 0; k0 < K; k0 += KT) {
    for (int i = tid; i < TS * KT; i += 256) {
      int r = i >> 4, kk = i & 15;
      As[kk][r] = A[(size_t)(row0 + r) * K + (k0 + kk)];
    }
    for (int i = tid; i < TS * KT; i += 256) {
      int c = i & 63, kk = i >> 6;
      Bs[kk][c] = Bm[(size_t)(k0 + kk) * N + (col0 + c)];
    }
    __syncthreads();
#pragma unroll
    for (int kk = 0; kk < KT; ++kk) {
      float4 av = *(const float4*)&As[kk][ty * 4];
      float4 bv = *(const float4*)&Bs[kk][tx * 4];
      float a[4] = {av.x, av.y, av.z, av.w};
      float b[4] = {bv.x, bv.y, bv.z, bv.w};
#pragma unroll
      for (int i = 0; i < 4; ++i)
#pragma unroll
        for (int j = 0; j < 4; ++j) acc[i][j] += a[i] * b[j];
    }
    __syncthreads();
  }
#pragma unroll
  for (int i = 0; i < 4; ++i)
#pragma unroll
    for (int j = 0; j < 4; ++j) {
      int r = row0 + ty * 4 + i, c = col0 + tx * 4 + j;
      C[(size_t)r * N + c] = acc[i][j] + bias[c];
    }
}

// ---------------- RoPE in-place on Q and K ---------------------------------
__global__ void rope_kernel(float* __restrict__ Q, float* __restrict__ Kp,
                            const float* __restrict__ freqs, int total) {
  int idx = blockIdx.x * blockDim.x + threadIdx.x;
  if (idx >= total) return;           // total = B*T*H*(Hd/2)
  int i = idx & 63;                   // pair index within head
  int rem = idx >> 6;                 // b*T*H + t*H + h flattened (b*T+t)*H+h
  int t = (rem / Hn) % Tn;
  float ang = freqs[t * 64 + i];
  float s, c;
  sincosf(ang, &s, &c);
  size_t base = (size_t)rem * Hd + 2 * i;
  float a = Q[base], b = Q[base + 1];
  Q[base]     = a * c - b * s;
  Q[base + 1] = a * s + b * c;
  a = Kp[base]; b = Kp[base + 1];
  Kp[base]     = a * c - b * s;
  Kp[base + 1] = a * s + b * c;
}

// ---------------- flash attention over latent dim 64 -----------------------
// grid: (T/64, B*H). block 256. Each thread: row r = tid>>2, col-slice s=tid&3.
__global__ __launch_bounds__(256) void attn_kernel(const float* __restrict__ qlat,
                                                   const float* __restrict__ klat,
                                                   const float* __restrict__ vlat,
                                                   float* __restrict__ olat) {
  __shared__ float Qs[64][Ln + 4];
  __shared__ float KV[64][Ln + 4];
  __shared__ float Ps[64][Ln + 4];
  const int bh = blockIdx.y;
  const int b = bh >> 4, h = bh & 15;
  const int qt = blockIdx.x;
  const int q0 = qt * 64;
  const int tid = threadIdx.x;
  const int r = tid >> 2, s = tid & 3;

  for (int i = tid; i < 64 * Ln; i += 256) {
    int rr = i >> 6, ll = i & 63;
    Qs[rr][ll] = qlat[((size_t)(b * Tn + q0 + rr) * Hn + h) * Ln + ll];
  }
  float m = -1e30f, lsum = 0.f;
  float o[16];
#pragma unroll
  for (int j = 0; j < 16; ++j) o[j] = 0.f;

  for (int kt = 0; kt <= qt; ++kt) {
    const int k0 = kt * 64;
    __syncthreads();  // prev PV reads of KV done; Qs visible on first iter
    for (int i = tid; i < 64 * Ln; i += 256) {
      int rr = i >> 6, ll = i & 63;
      KV[rr][ll] = klat[((size_t)(b * Tn + k0 + rr) * Hn + h) * Ln + ll];
    }
    __syncthreads();
    // S-tile: this thread's 16 columns (s*16 .. s*16+15) of row r
    float sv[16];
#pragma unroll
    for (int j = 0; j < 16; ++j) sv[j] = 0.f;
    for (int l = 0; l < Ln; l += 4) {
      float4 qv = *(const float4*)&Qs[r][l];
#pragma unroll
      for (int j = 0; j < 16; ++j) {
        float4 kv = *(const float4*)&KV[s * 16 + j][l];
        sv[j] += qv.x * kv.x + qv.y * kv.y + qv.z * kv.z + qv.w * kv.w;
      }
    }
    float tilemax = -1e30f;
#pragma unroll
    for (int j = 0; j < 16; ++j) {
      int cc = s * 16 + j;
      float v = sv[j] * SCALE;
      if (k0 + cc > q0 + r) v = -1e30f;  // causal mask
      sv[j] = v;
      tilemax = fmaxf(tilemax, v);
    }
    tilemax = fmaxf(tilemax, __shfl_xor(tilemax, 1));
    tilemax = fmaxf(tilemax, __shfl_xor(tilemax, 2));
    float mnew = fmaxf(m, tilemax);
    float alpha = __expf(m - mnew);
    float psum = 0.f;
#pragma unroll
    for (int j = 0; j < 16; ++j) {
      float p = __expf(sv[j] - mnew);
      Ps[r][s * 16 + j] = p;
      psum += p;
    }
    psum += __shfl_xor(psum, 1);
    psum += __shfl_xor(psum, 2);
    lsum = lsum * alpha + psum;
    m = mnew;
    __syncthreads();  // Ps visible; all S-reads of K done -> reuse KV for V
    for (int i = tid; i < 64 * Ln; i += 256) {
      int rr = i >> 6, ll = i & 63;
      KV[rr][ll] = vlat[((size_t)(b * Tn + k0 + rr) * Hn + h) * Ln + ll];
    }
    __syncthreads();
#pragma unroll
    for (int j = 0; j < 16; ++j) o[j] *= alpha;
    for (int l = 0; l < Ln; ++l) {
      float p = Ps[r][l];
#pragma unroll
      for (int j = 0; j < 16; ++j) o[j] += p * KV[l][s * 16 + j];
    }
  }
  float inv = 1.f / lsum;
#pragma unroll
  for (int j = 0; j < 16; ++j)
    olat[((size_t)(b * Tn + q0 + r) * Hn + h) * Ln + s * 16 + j] = o[j] * inv;
}

// ---------------------------------------------------------------------------
extern "C" void kernel_launch(void* const* d_in, const int* in_sizes, int n_in,
                              void* d_out, int out_size, void* d_ws, size_t ws_size,
                              hipStream_t stream) {
  const float* x     = (const float*)d_in[0];
  const float* freqs = (const float*)d_in[1];
  // d_in[2] = additive causal mask (unused; causal applied directly)
  const float* Wq  = (const float*)d_in[3];  const float* bq  = (const float*)d_in[4];
  const float* Wk  = (const float*)d_in[5];  const float* bk  = (const float*)d_in[6];
  const float* Wv  = (const float*)d_in[7];  const float* bv  = (const float*)d_in[8];
  const float* Wo  = (const float*)d_in[9];  const float* bo  = (const float*)d_in[10];
  const float* Wcq = (const float*)d_in[11]; const float* bcq = (const float*)d_in[12];
  const float* Wck = (const float*)d_in[13]; const float* bck = (const float*)d_in[14];
  const float* Wcv = (const float*)d_in[15]; const float* bcv = (const float*)d_in[16];
  const float* Wd  = (const float*)d_in[17]; const float* bd  = (const float*)d_in[18];
  float* out = (float*)d_out;

  const size_t BT = (size_t)Bsz * Tn;   // 4096
  const size_t nQ = BT * Dn;            // 8.39M floats
  const size_t nL = BT * Hn * Ln;       // 4.19M floats
  float* ws   = (float*)d_ws;
  float* Q    = ws;
  float* Kb   = Q + nQ;
  float* V    = Kb + nQ;
  float* qlat = V + nQ;
  float* klat = qlat + nL;
  float* vlat = klat + nL;
  float* olat = vlat + nL;
  float* tmp  = Q;                      // Q is dead after compression

  dim3 blk(256);
  // QKV projections: M=4096, N=2048, K=2048
  dim3 g1(Dn / TS, (int)(BT / TS));
  gemm_f32<<<g1, blk, 0, stream>>>(x, Wq, bq, Q,  (int)BT, Dn, Dn);
  gemm_f32<<<g1, blk, 0, stream>>>(x, Wk, bk, Kb, (int)BT, Dn, Dn);
  gemm_f32<<<g1, blk, 0, stream>>>(x, Wv, bv, V,  (int)BT, Dn, Dn);
  // RoPE on Q, K
  int pairs = (int)(BT * Hn * 64);
  rope_kernel<<<(pairs + 255) / 256, blk, 0, stream>>>(Q, Kb, freqs, pairs);
  // latent compression: M = B*T*H = 65536, K=128, N=64
  int MH = (int)(BT * Hn);
  dim3 g2(Ln / TS, MH / TS);
  gemm_f32<<<g2, blk, 0, stream>>>(Q,  Wcq, bcq, qlat, MH, Ln, Hd);
  gemm_f32<<<g2, blk, 0, stream>>>(Kb, Wck, bck, klat, MH, Ln, Hd);
  gemm_f32<<<g2, blk, 0, stream>>>(V,  Wcv, bcv, vlat, MH, Ln, Hd);
  // attention
  dim3 g3(Tn / 64, Bsz * Hn);
  attn_kernel<<<g3, blk, 0, stream>>>(qlat, klat, vlat, olat);
  // decompression: M=65536, K=64, N=128 -> tmp [B*T, D]
  dim3 g4(Hd / TS, MH / TS);
  gemm_f32<<<g4, blk, 0, stream>>>(olat, Wd, bd, tmp, MH, Hd, Ln);
  // output projection: M=4096, N=2048, K=2048
  gemm_f32<<<g1, blk, 0, stream>>>(tmp, Wo, bo, out, (int)BT, Dn, Dn);
}

// Round 2
// 2013.961 us; speedup vs baseline: 2.1911x; 2.1911x over previous
//
#include <hip/hip_runtime.h>
#include <hip/hip_bf16.h>

static constexpr int Bsz = 2;
static constexpr int Tn  = 2048;
static constexpr int Dn  = 2048;
static constexpr int Hn  = 16;
static constexpr int Ln  = 64;
static constexpr int Hd  = 128;
static constexpr float SCALE = 0.125f;  // 1/sqrt(64)

typedef short short8 __attribute__((ext_vector_type(8)));
typedef float f32x4 __attribute__((ext_vector_type(4)));
typedef unsigned short ushort8 __attribute__((ext_vector_type(8)));
typedef unsigned short ushort4v __attribute__((ext_vector_type(4)));

__device__ inline unsigned short bf_rne(float f) {
  union { float f; unsigned u; } x; x.f = f;
  unsigned r = x.u + 0x7fffu + ((x.u >> 16) & 1u);
  return (unsigned short)(r >> 16);
}
__device__ inline float bf_to_f(unsigned short h) {
  union { unsigned u; float f; } x; x.u = ((unsigned)h) << 16;
  return x.f;
}

// global -> LDS direct, 16B per lane
#define GL(g, l) __builtin_amdgcn_global_load_lds(                     \
    (const __attribute__((address_space(1))) void*)(g),                \
    (__attribute__((address_space(3))) void*)(l), 16, 0, 0)

// ---------- split fp32 -> bf16 hi/lo with per-32 K-window permutation ------
// permuted index p in [0,32): p = g*8 + h*4 + q  <->  k = h*16 + g*4 + q
// so each 16B block g holds k = {4g..4g+3, 16+4g..16+4g+3} (stacked x16 halves)
__global__ void split_permute(const float* __restrict__ A,
                              unsigned short* __restrict__ Oh,
                              unsigned short* __restrict__ Ol,
                              int nblk, int Kd) {
  int b = blockIdx.x * 256 + threadIdx.x;
  if (b >= nblk) return;
  int perRow = Kd >> 3;
  int m = b / perRow, gb = b - m * perRow;
  int w = gb >> 2, g = gb & 3;
  const float* src = A + (size_t)m * Kd + (w << 5) + (g << 2);
  float4 v0 = *(const float4*)src;
  float4 v1 = *(const float4*)(src + 16);
  float e[8] = {v0.x, v0.y, v0.z, v0.w, v1.x, v1.y, v1.z, v1.w};
  ushort8 hi, lo;
#pragma unroll
  for (int j = 0; j < 8; ++j) {
    unsigned short h = bf_rne(e[j]);
    hi[j] = h;
    lo[j] = bf_rne(e[j] - bf_to_f(h));
  }
  *(ushort8*)(Oh + (size_t)b * 8) = hi;
  *(ushort8*)(Ol + (size_t)b * 8) = lo;
}

// ---------- transpose W[K][N] -> WT[N][K] bf16 hi/lo, K-permuted -----------
__global__ __launch_bounds__(256) void transpose_split(
    const float* __restrict__ W, unsigned short* __restrict__ Th,
    unsigned short* __restrict__ Tl, int Kd, int Nd) {
  __shared__ float t[32][33];
  int k0 = blockIdx.x * 32, n0 = blockIdx.y * 32;
  int i = threadIdx.x;
  {
    int kk = i >> 3, nn = (i & 7) << 2;
    float4 v = *(const float4*)&W[(size_t)(k0 + kk) * Nd + n0 + nn];
    t[kk][nn] = v.x; t[kk][nn + 1] = v.y; t[kk][nn + 2] = v.z; t[kk][nn + 3] = v.w;
  }
  __syncthreads();
  int n = i >> 3, t2 = i & 7;
  int g = t2 >> 1, h = t2 & 1;
  int kbase = h * 16 + g * 4;
  ushort4v hi, lo;
#pragma unroll
  for (int j = 0; j < 4; ++j) {
    float f = t[kbase + j][n];
    unsigned short hh = bf_rne(f);
    hi[j] = hh;
    lo[j] = bf_rne(f - bf_to_f(hh));
  }
  size_t off = (size_t)(n0 + n) * Kd + k0 + t2 * 4;
  *(ushort4v*)(Th + off) = hi;
  *(ushort4v*)(Tl + off) = lo;
}

// ---------- bf16x3 MFMA GEMM: C = (Ah+Al)[M,K] @ (Bh+Bl)^T[N,K] + bias -----
// 128x128 tile, BK=32, 4 waves, 4x4 fragments of mfma_f32_16x16x32_bf16.
// LDS 16B-slot swizzle: slot ^= (row>>1)&3 (inverse applied on global source).
__global__ __launch_bounds__(256) void gemm_bf16x3(
    const unsigned short* __restrict__ Ah, const unsigned short* __restrict__ Al,
    const unsigned short* __restrict__ Bh, const unsigned short* __restrict__ Bl,
    const float* __restrict__ bias, float* __restrict__ C,
    int M, int N, int K) {
  __shared__ unsigned short s[4][128 * 32];  // Ah, Al, Bh, Bl tiles (8KB each)
  const int tid = threadIdx.x;
  const int lane = tid & 63;
  const int w = tid >> 6, wr = w >> 1, wc = w & 1;
  const int row0 = blockIdx.y * 128, col0 = blockIdx.x * 128;

  const int sr = tid >> 2, sq = tid & 3;
  const int sg = sq ^ ((sr >> 1) & 3);
  const size_t aoff0 = (size_t)(row0 + sr) * K + sg * 8;
  const size_t aoff1 = (size_t)(row0 + sr + 64) * K + sg * 8;
  const size_t boff0 = (size_t)(col0 + sr) * K + sg * 8;
  const size_t boff1 = (size_t)(col0 + sr + 64) * K + sg * 8;
  const int ldst0 = tid * 16, ldst1 = (tid + 256) * 16;

  f32x4 acc[4][4];
#pragma unroll
  for (int i2 = 0; i2 < 4; ++i2)
#pragma unroll
    for (int j2 = 0; j2 < 4; ++j2) acc[i2][j2] = (f32x4){0.f, 0.f, 0.f, 0.f};

  int fa[4], fb[4];
#pragma unroll
  for (int mi = 0; mi < 4; ++mi) {
    int ra = wr * 64 + mi * 16 + (lane & 15);
    fa[mi] = ra * 64 + (((lane >> 4) ^ ((ra >> 1) & 3)) << 4);
    int rb = wc * 64 + mi * 16 + (lane & 15);
    fb[mi] = rb * 64 + (((lane >> 4) ^ ((rb >> 1) & 3)) << 4);
  }

  for (int k0 = 0; k0 < K; k0 += 32) {
    __syncthreads();
    GL(Ah + aoff0 + k0, (char*)&s[0][0] + ldst0);
    GL(Ah + aoff1 + k0, (char*)&s[0][0] + ldst1);
    GL(Al + aoff0 + k0, (char*)&s[1][0] + ldst0);
    GL(Al + aoff1 + k0, (char*)&s[1][0] + ldst1);
    GL(Bh + boff0 + k0, (char*)&s[2][0] + ldst0);
    GL(Bh + boff1 + k0, (char*)&s[2][0] + ldst1);
    GL(Bl + boff0 + k0, (char*)&s[3][0] + ldst0);
    GL(Bl + boff1 + k0, (char*)&s[3][0] + ldst1);
    __syncthreads();
    short8 ah[4], al[4], bh[4], bl[4];
#pragma unroll
    for (int mi = 0; mi < 4; ++mi) {
      ah[mi] = *(const short8*)((const char*)&s[0][0] + fa[mi]);
      al[mi] = *(const short8*)((const char*)&s[1][0] + fa[mi]);
      bh[mi] = *(const short8*)((const char*)&s[2][0] + fb[mi]);
      bl[mi] = *(const short8*)((const char*)&s[3][0] + fb[mi]);
    }
#pragma unroll
    for (int mi = 0; mi < 4; ++mi)
#pragma unroll
      for (int ni = 0; ni < 4; ++ni) {
        acc[mi][ni] = __builtin_amdgcn_mfma_f32_16x16x32_bf16(ah[mi], bh[ni], acc[mi][ni], 0, 0, 0);
        acc[mi][ni] = __builtin_amdgcn_mfma_f32_16x16x32_bf16(ah[mi], bl[ni], acc[mi][ni], 0, 0, 0);
        acc[mi][ni] = __builtin_amdgcn_mfma_f32_16x16x32_bf16(al[mi], bh[ni], acc[mi][ni], 0, 0, 0);
      }
  }
#pragma unroll
  for (int ni = 0; ni < 4; ++ni) {
    int c = col0 + wc * 64 + ni * 16 + (lane & 15);
    float bv = bias[c];
#pragma unroll
    for (int mi = 0; mi < 4; ++mi) {
      int rr = row0 + wr * 64 + mi * 16 + ((lane >> 4) << 2);
#pragma unroll
      for (int r = 0; r < 4; ++r)
        C[(size_t)(rr + r) * N + c] = acc[mi][ni][r] + bv;
    }
  }
}

// ---------------- fp32 tiled GEMM (small latent GEMMs) ---------------------
static constexpr int TS = 64;
static constexpr int KT = 16;

__global__ __launch_bounds__(256) void gemm_f32(const float* __restrict__ A,
                                                const float* __restrict__ Bm,
                                                const float* __restrict__ bias,
                                                float* __restrict__ C,
                                                int M, int N, int K) {
  __shared__ float As[KT][TS + 4];
  __shared__ float Bs[KT][TS + 4];
  const int tid = threadIdx.x;
  const int tx = tid & 15, ty = tid >> 4;
  const int row0 = blockIdx.y * TS, col0 = blockIdx.x * TS;
  float acc[4][4] = {};
  for (int k0 = 0; k0 < K; k0 += KT) {
    for (int i = tid; i < TS * KT; i += 256) {
      int r = i >> 4, kk = i & 15;
      As[kk][r] = A[(size_t)(row0 + r) * K + (k0 + kk)];
    }
    for (int i = tid; i < TS * KT; i += 256) {
      int c = i & 63, kk = i >> 6;
      Bs[kk][c] = Bm[(size_t)(k0 + kk) * N + (col0 + c)];
    }
    __syncthreads();
#pragma unroll
    for (int kk = 0; kk < KT; ++kk) {
      float4 av = *(const float4*)&As[kk][ty * 4];
      float4 bv = *(const float4*)&Bs[kk][tx * 4];
      float a[4] = {av.x, av.y, av.z, av.w};
      float b[4] = {bv.x, bv.y, bv.z, bv.w};
#pragma unroll
      for (int i = 0; i < 4; ++i)
#pragma unroll
        for (int j = 0; j < 4; ++j) acc[i][j] += a[i] * b[j];
    }
    __syncthreads();
  }
#pragma unroll
  for (int i = 0; i < 4; ++i)
#pragma unroll
    for (int j = 0; j < 4; ++j) {
      int r = row0 + ty * 4 + i, c = col0 + tx * 4 + j;
      C[(size_t)r * N + c] = acc[i][j] + bias[c];
    }
}

// ---------------- RoPE in-place on Q and K ---------------------------------
__global__ void rope_kernel(float* __restrict__ Q, float* __restrict__ Kp,
                            const float* __restrict__ freqs, int total) {
  int idx = blockIdx.x * blockDim.x + threadIdx.x;
  if (idx >= total) return;
  int i = idx & 63;
  int rem = idx >> 6;
  int t = (rem / Hn) % Tn;
  float ang = freqs[t * 64 + i];
  float s, c;
  sincosf(ang, &s, &c);
  size_t base = (size_t)rem * Hd + 2 * i;
  float a = Q[base], b = Q[base + 1];
  Q[base]     = a * c - b * s;
  Q[base + 1] = a * s + b * c;
  a = Kp[base]; b = Kp[base + 1];
  Kp[base]     = a * c - b * s;
  Kp[base + 1] = a * s + b * c;
}

// ---------------- flash attention over latent dim 64 (fp32) ----------------
__global__ __launch_bounds__(256) void attn_kernel(const float* __restrict__ qlat,
                                                   const float* __restrict__ klat,
                                                   const float* __restrict__ vlat,
                                                   float* __restrict__ olat) {
  __shared__ float Qs[64][Ln + 4];
  __shared__ float KV[64][Ln + 4];
  __shared__ float Ps[64][Ln + 4];
  const int bh = blockIdx.y;
  const int b = bh >> 4, h = bh & 15;
  const int qt = blockIdx.x;
  const int q0 = qt * 64;
  const int tid = threadIdx.x;
  const int r = tid >> 2, s = tid & 3;

  for (int i = tid; i < 64 * Ln; i += 256) {
    int rr = i >> 6, ll = i & 63;
    Qs[rr][ll] = qlat[((size_t)(b * Tn + q0 + rr) * Hn + h) * Ln + ll];
  }
  float m = -1e30f, lsum = 0.f;
  float o[16];
#pragma unroll
  for (int j = 0; j < 16; ++j) o[j] = 0.f;

  for (int kt = 0; kt <= qt; ++kt) {
    const int k0 = kt * 64;
    __syncthreads();
    for (int i = tid; i < 64 * Ln; i += 256) {
      int rr = i >> 6, ll = i & 63;
      KV[rr][ll] = klat[((size_t)(b * Tn + k0 + rr) * Hn + h) * Ln + ll];
    }
    __syncthreads();
    float sv[16];
#pragma unroll
    for (int j = 0; j < 16; ++j) sv[j] = 0.f;
    for (int l = 0; l < Ln; l += 4) {
      float4 qv = *(const float4*)&Qs[r][l];
#pragma unroll
      for (int j = 0; j < 16; ++j) {
        float4 kv = *(const float4*)&KV[s * 16 + j][l];
        sv[j] += qv.x * kv.x + qv.y * kv.y + qv.z * kv.z + qv.w * kv.w;
      }
    }
    float tilemax = -1e30f;
#pragma unroll
    for (int j = 0; j < 16; ++j) {
      int cc = s * 16 + j;
      float v = sv[j] * SCALE;
      if (k0 + cc > q0 + r) v = -1e30f;
      sv[j] = v;
      tilemax = fmaxf(tilemax, v);
    }
    tilemax = fmaxf(tilemax, __shfl_xor(tilemax, 1));
    tilemax = fmaxf(tilemax, __shfl_xor(tilemax, 2));
    float mnew = fmaxf(m, tilemax);
    float alpha = __expf(m - mnew);
    float psum = 0.f;
#pragma unroll
    for (int j = 0; j < 16; ++j) {
      float p = __expf(sv[j] - mnew);
      Ps[r][s * 16 + j] = p;
      psum += p;
    }
    psum += __shfl_xor(psum, 1);
    psum += __shfl_xor(psum, 2);
    lsum = lsum * alpha + psum;
    m = mnew;
    __syncthreads();
    for (int i = tid; i < 64 * Ln; i += 256) {
      int rr = i >> 6, ll = i & 63;
      KV[rr][ll] = vlat[((size_t)(b * Tn + k0 + rr) * Hn + h) * Ln + ll];
    }
    __syncthreads();
#pragma unroll
    for (int j = 0; j < 16; ++j) o[j] *= alpha;
    for (int l = 0; l < Ln; ++l) {
      float p = Ps[r][l];
#pragma unroll
      for (int j = 0; j < 16; ++j) o[j] += p * KV[l][s * 16 + j];
    }
  }
  float inv = 1.f / lsum;
#pragma unroll
  for (int j = 0; j < 16; ++j)
    olat[((size_t)(b * Tn + q0 + r) * Hn + h) * Ln + s * 16 + j] = o[j] * inv;
}

// ---------------------------------------------------------------------------
extern "C" void kernel_launch(void* const* d_in, const int* in_sizes, int n_in,
                              void* d_out, int out_size, void* d_ws, size_t ws_size,
                              hipStream_t stream) {
  const float* x     = (const float*)d_in[0];
  const float* freqs = (const float*)d_in[1];
  const float* Wq  = (const float*)d_in[3];  const float* bq  = (const float*)d_in[4];
  const float* Wk  = (const float*)d_in[5];  const float* bk  = (const float*)d_in[6];
  const float* Wv  = (const float*)d_in[7];  const float* bv  = (const float*)d_in[8];
  const float* Wo  = (const float*)d_in[9];  const float* bo  = (const float*)d_in[10];
  const float* Wcq = (const float*)d_in[11]; const float* bcq = (const float*)d_in[12];
  const float* Wck = (const float*)d_in[13]; const float* bck = (const float*)d_in[14];
  const float* Wcv = (const float*)d_in[15]; const float* bcv = (const float*)d_in[16];
  const float* Wd  = (const float*)d_in[17]; const float* bd  = (const float*)d_in[18];
  float* out = (float*)d_out;

  const size_t BT = (size_t)Bsz * Tn;   // 4096
  const size_t nQ = BT * Dn;            // 8.39M
  const size_t nL = BT * Hn * Ln;       // 4.19M
  const size_t nW = (size_t)Dn * Dn;    // 4.19M
  float* ws   = (float*)d_ws;
  float* Q    = ws;
  float* Kb   = Q + nQ;
  float* V    = Kb + nQ;
  float* qlat = V + nQ;
  float* klat = qlat + nL;
  float* vlat = klat + nL;
  float* olat = vlat + nL;
  unsigned short* xh  = (unsigned short*)(olat + nL);
  unsigned short* xl  = xh + nQ;
  unsigned short* wth = xl + nQ;
  unsigned short* wtl = wth + nW;
  float* tmp = Q;  // reuse after compression

  dim3 blk(256);
  const int M = (int)BT, N = Dn, K = Dn;
  dim3 gg(N / 128, M / 128);            // 16 x 32
  dim3 gt(K / 32, N / 32);              // 64 x 64
  int nblkA = (int)(nQ / 8);

  // x -> bf16 hi/lo (K-permuted)
  split_permute<<<(nblkA + 255) / 256, blk, 0, stream>>>(x, xh, xl, nblkA, K);
  // QKV projections via bf16x3 MFMA
  transpose_split<<<gt, blk, 0, stream>>>(Wq, wth, wtl, K, N);
  gemm_bf16x3<<<gg, blk, 0, stream>>>(xh, xl, wth, wtl, bq, Q, M, N, K);
  transpose_split<<<gt, blk, 0, stream>>>(Wk, wth, wtl, K, N);
  gemm_bf16x3<<<gg, blk, 0, stream>>>(xh, xl, wth, wtl, bk, Kb, M, N, K);
  transpose_split<<<gt, blk, 0, stream>>>(Wv, wth, wtl, K, N);
  gemm_bf16x3<<<gg, blk, 0, stream>>>(xh, xl, wth, wtl, bv, V, M, N, K);
  // RoPE
  int pairs = (int)(BT * Hn * 64);
  rope_kernel<<<(pairs + 255) / 256, blk, 0, stream>>>(Q, Kb, freqs, pairs);
  // latent compression (fp32)
  int MH = (int)(BT * Hn);
  dim3 g2(Ln / TS, MH / TS);
  gemm_f32<<<g2, blk, 0, stream>>>(Q,  Wcq, bcq, qlat, MH, Ln, Hd);
  gemm_f32<<<g2, blk, 0, stream>>>(Kb, Wck, bck, klat, MH, Ln, Hd);
  gemm_f32<<<g2, blk, 0, stream>>>(V,  Wcv, bcv, vlat, MH, Ln, Hd);
  // attention
  dim3 g3(Tn / 64, Bsz * Hn);
  attn_kernel<<<g3, blk, 0, stream>>>(qlat, klat, vlat, olat);
  // decompression (fp32): [MH,64] @ [64,128] -> tmp
  dim3 g4(Hd / TS, MH / TS);
  gemm_f32<<<g4, blk, 0, stream>>>(olat, Wd, bd, tmp, MH, Hd, Ln);
  // output projection via bf16x3 MFMA (tmp split reuses xh/xl)
  split_permute<<<(nblkA + 255) / 256, blk, 0, stream>>>(tmp, xh, xl, nblkA, K);
  transpose_split<<<gt, blk, 0, stream>>>(Wo, wth, wtl, K, N);
  gemm_bf16x3<<<gg, blk, 0, stream>>>(xh, xl, wth, wtl, bo, out, M, N, K);
}

// Round 3
// 689.872 us; speedup vs baseline: 6.3965x; 2.9193x over previous
//
#include <hip/hip_runtime.h>
#include <hip/hip_bf16.h>

static constexpr int Bsz = 2;
static constexpr int Tn  = 2048;
static constexpr int Dn  = 2048;
static constexpr int Hn  = 16;
static constexpr int Ln  = 64;
static constexpr int Hd  = 128;
static constexpr float SL2E = 0.125f * 1.44269504088896f;  // SCALE * log2(e)

typedef short short8 __attribute__((ext_vector_type(8)));
typedef float f32x4 __attribute__((ext_vector_type(4)));
typedef unsigned short ushort8 __attribute__((ext_vector_type(8)));
typedef unsigned short ushort4v __attribute__((ext_vector_type(4)));
typedef unsigned short u16;

__device__ inline unsigned short bf_rne(float f) {
  union { float f; unsigned u; } x; x.f = f;
  unsigned r = x.u + 0x7fffu + ((x.u >> 16) & 1u);
  return (unsigned short)(r >> 16);
}
__device__ inline float bf_to_f(unsigned short h) {
  union { unsigned u; float f; } x; x.u = ((unsigned)h) << 16;
  return x.f;
}

// global -> LDS direct, 16B per lane (GEMM staging only; linear dest)
#define GL(g, l) __builtin_amdgcn_global_load_lds(                     \
    (const __attribute__((address_space(1))) void*)(g),                \
    (__attribute__((address_space(3))) void*)(l), 16, 0, 0)

// ---------- split fp32 -> bf16 hi/lo with per-32 K-window permutation ------
__global__ void split_permute(const float* __restrict__ A,
                              unsigned short* __restrict__ Oh,
                              unsigned short* __restrict__ Ol,
                              int nblk, int Kd) {
  int b = blockIdx.x * 256 + threadIdx.x;
  if (b >= nblk) return;
  int perRow = Kd >> 3;
  int m = b / perRow, gb = b - m * perRow;
  int w = gb >> 2, g = gb & 3;
  const float* src = A + (size_t)m * Kd + (w << 5) + (g << 2);
  float4 v0 = *(const float4*)src;
  float4 v1 = *(const float4*)(src + 16);
  float e[8] = {v0.x, v0.y, v0.z, v0.w, v1.x, v1.y, v1.z, v1.w};
  ushort8 hi, lo;
#pragma unroll
  for (int j = 0; j < 8; ++j) {
    unsigned short h = bf_rne(e[j]);
    hi[j] = h;
    lo[j] = bf_rne(e[j] - bf_to_f(h));
  }
  *(ushort8*)(Oh + (size_t)b * 8) = hi;
  *(ushort8*)(Ol + (size_t)b * 8) = lo;
}

// ---------- transpose W[K][N] -> WT[N][K] bf16 hi/lo, K-permuted -----------
__global__ __launch_bounds__(256) void transpose_split(
    const float* __restrict__ W, unsigned short* __restrict__ Th,
    unsigned short* __restrict__ Tl, int Kd, int Nd) {
  __shared__ float t[32][33];
  int k0 = blockIdx.x * 32, n0 = blockIdx.y * 32;
  int i = threadIdx.x;
  {
    int kk = i >> 3, nn = (i & 7) << 2;
    float4 v = *(const float4*)&W[(size_t)(k0 + kk) * Nd + n0 + nn];
    t[kk][nn] = v.x; t[kk][nn + 1] = v.y; t[kk][nn + 2] = v.z; t[kk][nn + 3] = v.w;
  }
  __syncthreads();
  int n = i >> 3, t2 = i & 7;
  int g = t2 >> 1, h = t2 & 1;
  int kbase = h * 16 + g * 4;
  ushort4v hi, lo;
#pragma unroll
  for (int j = 0; j < 4; ++j) {
    float f = t[kbase + j][n];
    unsigned short hh = bf_rne(f);
    hi[j] = hh;
    lo[j] = bf_rne(f - bf_to_f(hh));
  }
  size_t off = (size_t)(n0 + n) * Kd + k0 + t2 * 4;
  *(ushort4v*)(Th + off) = hi;
  *(ushort4v*)(Tl + off) = lo;
}

// ---------- bf16x3 MFMA GEMM: C = (Ah+Al)[M,K] @ (Bh+Bl)^T[N,K] + bias -----
__global__ __launch_bounds__(256) void gemm_bf16x3(
    const unsigned short* __restrict__ Ah, const unsigned short* __restrict__ Al,
    const unsigned short* __restrict__ Bh, const unsigned short* __restrict__ Bl,
    const float* __restrict__ bias, float* __restrict__ C,
    int M, int N, int K) {
  __shared__ unsigned short s[4][128 * 32];
  const int tid = threadIdx.x;
  const int lane = tid & 63;
  const int w = tid >> 6, wr = w >> 1, wc = w & 1;
  const int row0 = blockIdx.y * 128, col0 = blockIdx.x * 128;

  const int sr = tid >> 2, sq = tid & 3;
  const int sg = sq ^ ((sr >> 1) & 3);
  const size_t aoff0 = (size_t)(row0 + sr) * K + sg * 8;
  const size_t aoff1 = (size_t)(row0 + sr + 64) * K + sg * 8;
  const size_t boff0 = (size_t)(col0 + sr) * K + sg * 8;
  const size_t boff1 = (size_t)(col0 + sr + 64) * K + sg * 8;
  const int ldst0 = tid * 16, ldst1 = (tid + 256) * 16;

  f32x4 acc[4][4];
#pragma unroll
  for (int i2 = 0; i2 < 4; ++i2)
#pragma unroll
    for (int j2 = 0; j2 < 4; ++j2) acc[i2][j2] = (f32x4){0.f, 0.f, 0.f, 0.f};

  int fa[4], fb[4];
#pragma unroll
  for (int mi = 0; mi < 4; ++mi) {
    int ra = wr * 64 + mi * 16 + (lane & 15);
    fa[mi] = ra * 64 + (((lane >> 4) ^ ((ra >> 1) & 3)) << 4);
    int rb = wc * 64 + mi * 16 + (lane & 15);
    fb[mi] = rb * 64 + (((lane >> 4) ^ ((rb >> 1) & 3)) << 4);
  }

  for (int k0 = 0; k0 < K; k0 += 32) {
    __syncthreads();
    GL(Ah + aoff0 + k0, (char*)&s[0][0] + ldst0);
    GL(Ah + aoff1 + k0, (char*)&s[0][0] + ldst1);
    GL(Al + aoff0 + k0, (char*)&s[1][0] + ldst0);
    GL(Al + aoff1 + k0, (char*)&s[1][0] + ldst1);
    GL(Bh + boff0 + k0, (char*)&s[2][0] + ldst0);
    GL(Bh + boff1 + k0, (char*)&s[2][0] + ldst1);
    GL(Bl + boff0 + k0, (char*)&s[3][0] + ldst0);
    GL(Bl + boff1 + k0, (char*)&s[3][0] + ldst1);
    __syncthreads();
    short8 ah[4], al[4], bh[4], bl[4];
#pragma unroll
    for (int mi = 0; mi < 4; ++mi) {
      ah[mi] = *(const short8*)((const char*)&s[0][0] + fa[mi]);
      al[mi] = *(const short8*)((const char*)&s[1][0] + fa[mi]);
      bh[mi] = *(const short8*)((const char*)&s[2][0] + fb[mi]);
      bl[mi] = *(const short8*)((const char*)&s[3][0] + fb[mi]);
    }
#pragma unroll
    for (int mi = 0; mi < 4; ++mi)
#pragma unroll
      for (int ni = 0; ni < 4; ++ni) {
        acc[mi][ni] = __builtin_amdgcn_mfma_f32_16x16x32_bf16(ah[mi], bh[ni], acc[mi][ni], 0, 0, 0);
        acc[mi][ni] = __builtin_amdgcn_mfma_f32_16x16x32_bf16(ah[mi], bl[ni], acc[mi][ni], 0, 0, 0);
        acc[mi][ni] = __builtin_amdgcn_mfma_f32_16x16x32_bf16(al[mi], bh[ni], acc[mi][ni], 0, 0, 0);
      }
  }
#pragma unroll
  for (int ni = 0; ni < 4; ++ni) {
    int c = col0 + wc * 64 + ni * 16 + (lane & 15);
    float bv = bias[c];
#pragma unroll
    for (int mi = 0; mi < 4; ++mi) {
      int rr = row0 + wr * 64 + mi * 16 + ((lane >> 4) << 2);
#pragma unroll
      for (int r = 0; r < 4; ++r)
        C[(size_t)(rr + r) * N + c] = acc[mi][ni][r] + bv;
    }
  }
}

// ---------- fused RoPE + latent compression for Q/K ------------------------
// out: [B*H][T][64] bf16, lat index permuted per-32-window.
__global__ __launch_bounds__(256) void compress_qk(
    const float* __restrict__ src, const float* __restrict__ Wc,
    const float* __restrict__ bc, const float* __restrict__ freqs,
    u16* __restrict__ dst) {
  __shared__ float q_lds[64][132];
  __shared__ float w_lds[128 * 64];
  const int tid = threadIdx.x;
  const int t0 = blockIdx.x * 64;
  const int bh = blockIdx.y, b = bh >> 4, h = bh & 15;
  for (int i = tid; i < 2048; i += 256)
    ((float4*)w_lds)[i] = ((const float4*)Wc)[i];
  const int r = tid >> 2, seg = tid & 3;
  const float* qp = src + ((size_t)(b * Tn + t0 + r)) * Dn + h * 128 + seg * 32;
  const float* fp = freqs + (size_t)(t0 + r) * 64 + seg * 16;
  float fr[16];
#pragma unroll
  for (int j = 0; j < 4; ++j) *(float4*)&fr[4 * j] = ((const float4*)fp)[j];
#pragma unroll
  for (int j = 0; j < 8; ++j) {
    float4 v = ((const float4*)qp)[j];
    float s0, c0, s1, c1;
    sincosf(fr[2 * j], &s0, &c0);
    sincosf(fr[2 * j + 1], &s1, &c1);
    q_lds[r][seg * 32 + 4 * j + 0] = v.x * c0 - v.y * s0;
    q_lds[r][seg * 32 + 4 * j + 1] = v.x * s0 + v.y * c0;
    q_lds[r][seg * 32 + 4 * j + 2] = v.z * c1 - v.w * s1;
    q_lds[r][seg * 32 + 4 * j + 3] = v.z * s1 + v.w * c1;
  }
  __syncthreads();
  const int l0 = seg * 16;
  float acc[16];
#pragma unroll
  for (int i = 0; i < 16; ++i) acc[i] = bc[l0 + i];
  for (int k = 0; k < 128; ++k) {
    float qv = q_lds[r][k];
    const float* wr = &w_lds[k * 64 + l0];
#pragma unroll
    for (int i = 0; i < 16; ++i) acc[i] += qv * wr[i];
  }
  const int w32 = l0 >> 5, h4 = (l0 >> 4) & 1;
  u16* op = dst + ((size_t)bh * Tn + t0 + r) * 64 + w32 * 32 + h4 * 4;
#pragma unroll
  for (int g = 0; g < 4; ++g) {
    ushort4v u;
#pragma unroll
    for (int q = 0; q < 4; ++q) u[q] = bf_rne(acc[g * 4 + q]);
    *(ushort4v*)(op + g * 8) = u;
  }
}

// ---------- latent compression for V, output transposed --------------------
// out: [B*H][64 lat][T] bf16, t index permuted per-32-window.
__global__ __launch_bounds__(256) void compress_v(
    const float* __restrict__ src, const float* __restrict__ Wc,
    const float* __restrict__ bc, u16* __restrict__ dstT) {
  __shared__ float v_lds[64][132];
  __shared__ float w_lds[128 * 64];
  __shared__ u16 o_lds[64][64];
  const int tid = threadIdx.x;
  const int t0 = blockIdx.x * 64;
  const int bh = blockIdx.y, b = bh >> 4, h = bh & 15;
  for (int i = tid; i < 2048; i += 256)
    ((float4*)w_lds)[i] = ((const float4*)Wc)[i];
  const int r = tid >> 2, seg = tid & 3;
  const float* vp = src + ((size_t)(b * Tn + t0 + r)) * Dn + h * 128 + seg * 32;
#pragma unroll
  for (int j = 0; j < 8; ++j)
    *(float4*)&v_lds[r][seg * 32 + 4 * j] = ((const float4*)vp)[j];
  __syncthreads();
  const int l0 = seg * 16;
  float acc[16];
#pragma unroll
  for (int i = 0; i < 16; ++i) acc[i] = bc[l0 + i];
  for (int k = 0; k < 128; ++k) {
    float vv = v_lds[r][k];
    const float* wr = &w_lds[k * 64 + l0];
#pragma unroll
    for (int i = 0; i < 16; ++i) acc[i] += vv * wr[i];
  }
  // stage to LDS with 4-granule xor swizzle (conflict-break for transpose read)
#pragma unroll
  for (int g = 0; g < 4; ++g) {
    ushort4v u;
#pragma unroll
    for (int q = 0; q < 4; ++q) u[q] = bf_rne(acc[g * 4 + q]);
    *(ushort4v*)&o_lds[r][l0 + ((g ^ (r & 3)) << 2)] = u;
  }
  __syncthreads();
  const int lat = tid >> 2, tseg = tid & 3;
  const int tw = tseg >> 1, h4 = tseg & 1;
  u16 vals[16];
#pragma unroll
  for (int i = 0; i < 16; ++i)
    vals[i] = o_lds[tseg * 16 + i][lat ^ ((i & 3) << 2)];
  u16* dp = dstT + ((size_t)bh * 64 + lat) * Tn + t0 + tw * 32 + h4 * 4;
#pragma unroll
  for (int g = 0; g < 4; ++g) {
    ushort4v u = {vals[g * 4 + 0], vals[g * 4 + 1], vals[g * 4 + 2], vals[g * 4 + 3]};
    *(ushort4v*)(dp + g * 8) = u;
  }
}

// ---------- MFMA flash attention (latent dim 64, causal) -------------------
// grid (T/128 reversed, B*H), 4 waves. S^T = mfma(K,Q); P stays in registers.
__global__ __launch_bounds__(256) void attn_mfma(
    const u16* __restrict__ qlat, const u16* __restrict__ klat,
    const u16* __restrict__ vlatT, float* __restrict__ olatT) {
  __shared__ u16 Ks[64 * 72];  // [kv][lat_perm], row stride 144B (2-way max)
  __shared__ u16 Vs[64 * 72];  // [lat][t_perm]
  const int tid = threadIdx.x;
  const int lane = tid & 63;
  const int w = tid >> 6;
  const int bh = blockIdx.y;
  const int q0 = (int)(gridDim.x - 1 - blockIdx.x) * 128;  // big blocks first
  const int qw = q0 + w * 32;
  const u16* ql = qlat + (size_t)bh * Tn * 64;
  const u16* kl = klat + (size_t)bh * Tn * 64;
  const u16* vt = vlatT + (size_t)bh * 64 * Tn;
  float* ot = olatT + (size_t)bh * 64 * Tn;
  const int l15 = lane & 15, lg = lane >> 4;

  short8 qf[2][2];
#pragma unroll
  for (int nf = 0; nf < 2; ++nf)
#pragma unroll
    for (int ks = 0; ks < 2; ++ks)
      qf[nf][ks] = *(const short8*)(ql + (size_t)(qw + nf * 16 + l15) * 64 + (ks * 4 + lg) * 8);

  f32x4 accO[4][2];
#pragma unroll
  for (int mi = 0; mi < 4; ++mi)
#pragma unroll
    for (int nf = 0; nf < 2; ++nf) accO[mi][nf] = (f32x4){0.f, 0.f, 0.f, 0.f};
  float mrow[2] = {-1e30f, -1e30f}, lrow[2] = {0.f, 0.f};

  const int srow = tid >> 2, spair = tid & 3;
  u16* ksw = &Ks[srow * 72 + spair * 16];
  u16* vsw = &Vs[srow * 72 + spair * 16];
  const u16* kgp = kl + (size_t)srow * 64 + spair * 16;
  const u16* vgp = vt + (size_t)srow * Tn + spair * 16;

  const int ntiles = q0 / 64 + 2;
  for (int kt = 0; kt < ntiles; ++kt) {
    const int k0 = kt * 64;
    __syncthreads();
    *(short8*)ksw       = *(const short8*)(kgp + (size_t)k0 * 64);
    *(short8*)(ksw + 8) = *(const short8*)(kgp + (size_t)k0 * 64 + 8);
    *(short8*)vsw       = *(const short8*)(vgp + k0);
    *(short8*)(vsw + 8) = *(const short8*)(vgp + k0 + 8);
    __syncthreads();
    if (k0 > qw + 31) continue;  // no barrier below: safe wave-divergent skip

    f32x4 s4[4][2];
#pragma unroll
    for (int mi = 0; mi < 4; ++mi) {
      s4[mi][0] = (f32x4){0.f, 0.f, 0.f, 0.f};
      s4[mi][1] = (f32x4){0.f, 0.f, 0.f, 0.f};
    }
#pragma unroll
    for (int ks = 0; ks < 2; ++ks) {
      short8 kf[4];
#pragma unroll
      for (int mi = 0; mi < 4; ++mi)
        kf[mi] = *(const short8*)&Ks[(mi * 16 + l15) * 72 + (ks * 4 + lg) * 8];
#pragma unroll
      for (int mi = 0; mi < 4; ++mi) {
        s4[mi][0] = __builtin_amdgcn_mfma_f32_16x16x32_bf16(kf[mi], qf[0][ks], s4[mi][0], 0, 0, 0);
        s4[mi][1] = __builtin_amdgcn_mfma_f32_16x16x32_bf16(kf[mi], qf[1][ks], s4[mi][1], 0, 0, 0);
      }
    }
    short8 pf[2][2];
#pragma unroll
    for (int nf = 0; nf < 2; ++nf) {
      const int qidx = qw + nf * 16 + l15;
      float p[4][4];
      float tmax = -1e30f;
#pragma unroll
      for (int mi = 0; mi < 4; ++mi)
#pragma unroll
        for (int rr = 0; rr < 4; ++rr) {
          int kv = k0 + mi * 16 + lg * 4 + rr;
          float v = s4[mi][nf][rr] * SL2E;
          if (kv > qidx) v = -1e30f;
          p[mi][rr] = v;
          tmax = fmaxf(tmax, v);
        }
      tmax = fmaxf(tmax, __shfl_xor(tmax, 16));
      tmax = fmaxf(tmax, __shfl_xor(tmax, 32));
      float mnew = fmaxf(mrow[nf], tmax);
      float alpha = exp2f(mrow[nf] - mnew);
      mrow[nf] = mnew;
      float psum = 0.f;
#pragma unroll
      for (int mi = 0; mi < 4; ++mi)
#pragma unroll
        for (int rr = 0; rr < 4; ++rr) {
          float e = exp2f(p[mi][rr] - mnew);
          unsigned hb = __float_as_uint(e) & 0xffff0000u;  // trunc to bf16
          psum += __uint_as_float(hb);                     // sum of ROUNDED p
          p[mi][rr] = __uint_as_float(hb);
        }
      psum += __shfl_xor(psum, 16);
      psum += __shfl_xor(psum, 32);
      lrow[nf] = lrow[nf] * alpha + psum;
#pragma unroll
      for (int mi = 0; mi < 4; ++mi)
#pragma unroll
        for (int rr = 0; rr < 4; ++rr) accO[mi][nf][rr] *= alpha;
#pragma unroll
      for (int ks = 0; ks < 2; ++ks) {
        short8 f;
#pragma unroll
        for (int rr = 0; rr < 4; ++rr) {
          f[rr]     = (short)(__float_as_uint(p[2 * ks][rr]) >> 16);
          f[4 + rr] = (short)(__float_as_uint(p[2 * ks + 1][rr]) >> 16);
        }
        pf[nf][ks] = f;
      }
    }
#pragma unroll
    for (int ks = 0; ks < 2; ++ks) {
      short8 vf[4];
#pragma unroll
      for (int mi = 0; mi < 4; ++mi)
        vf[mi] = *(const short8*)&Vs[(mi * 16 + l15) * 72 + (ks * 4 + lg) * 8];
#pragma unroll
      for (int mi = 0; mi < 4; ++mi) {
        accO[mi][0] = __builtin_amdgcn_mfma_f32_16x16x32_bf16(vf[mi], pf[0][ks], accO[mi][0], 0, 0, 0);
        accO[mi][1] = __builtin_amdgcn_mfma_f32_16x16x32_bf16(vf[mi], pf[1][ks], accO[mi][1], 0, 0, 0);
      }
    }
  }
#pragma unroll
  for (int nf = 0; nf < 2; ++nf) {
    float inv = 1.f / lrow[nf];
    int q = qw + nf * 16 + l15;
#pragma unroll
    for (int mi = 0; mi < 4; ++mi)
#pragma unroll
      for (int rr = 0; rr < 4; ++rr)
        ot[(size_t)(mi * 16 + lg * 4 + rr) * Tn + q] = accO[mi][nf][rr] * inv;
  }
}

// ---------- decompression + hi/lo split for out-projection -----------------
__global__ __launch_bounds__(256) void decompress_split(
    const float* __restrict__ olatT, const float* __restrict__ Wd,
    const float* __restrict__ bd, u16* __restrict__ xh, u16* __restrict__ xl) {
  __shared__ float o_lds[64][68];
  __shared__ float w_lds[64 * 132];  // staggered: idx = lat*132 + d + (d>>5)
  const int tid = threadIdx.x;
  const int t0 = blockIdx.x * 64;
  const int bh = blockIdx.y, b = bh >> 4, h = bh & 15;
  const int lat = tid >> 2, seg = tid & 3;
  const float* op = olatT + ((size_t)bh * 64 + lat) * Tn + t0 + seg * 16;
#pragma unroll
  for (int j = 0; j < 4; ++j)
    *(float4*)&o_lds[lat][seg * 16 + 4 * j] = ((const float4*)op)[j];
  for (int i = tid; i < 2048; i += 256) {
    float4 wv = ((const float4*)Wd)[i];
    int l = (i * 4) >> 7, d = (i * 4) & 127;
    float* wp = &w_lds[l * 132 + d + (d >> 5)];
    wp[0] = wv.x; wp[1] = wv.y; wp[2] = wv.z; wp[3] = wv.w;
  }
  __syncthreads();
  const int r = tid >> 2, d0 = (tid & 3) * 32;
  const int dof = d0 + (d0 >> 5);
  float acc[32];
#pragma unroll
  for (int j = 0; j < 32; ++j) acc[j] = bd[d0 + j];
  for (int l = 0; l < 64; ++l) {
    float ov = o_lds[l][r];
    const float* wr = &w_lds[l * 132 + dof];
#pragma unroll
    for (int j = 0; j < 32; ++j) acc[j] += ov * wr[j];
  }
  const int cb = h * 128 + d0;
  u16* hp = xh + ((size_t)(b * Tn + t0 + r)) * Dn + cb;
  u16* lp = xl + ((size_t)(b * Tn + t0 + r)) * Dn + cb;
#pragma unroll
  for (int h4 = 0; h4 < 2; ++h4)
#pragma unroll
    for (int g = 0; g < 4; ++g) {
      ushort4v uh, ul;
#pragma unroll
      for (int q = 0; q < 4; ++q) {
        float f = acc[h4 * 16 + g * 4 + q];
        unsigned short hb = bf_rne(f);
        uh[q] = hb;
        ul[q] = bf_rne(f - bf_to_f(hb));
      }
      *(ushort4v*)(hp + g * 8 + h4 * 4) = uh;
      *(ushort4v*)(lp + g * 8 + h4 * 4) = ul;
    }
}

// ---------------------------------------------------------------------------
extern "C" void kernel_launch(void* const* d_in, const int* in_sizes, int n_in,
                              void* d_out, int out_size, void* d_ws, size_t ws_size,
                              hipStream_t stream) {
  const float* x     = (const float*)d_in[0];
  const float* freqs = (const float*)d_in[1];
  const float* Wq  = (const float*)d_in[3];  const float* bq  = (const float*)d_in[4];
  const float* Wk  = (const float*)d_in[5];  const float* bk  = (const float*)d_in[6];
  const float* Wv  = (const float*)d_in[7];  const float* bv  = (const float*)d_in[8];
  const float* Wo  = (const float*)d_in[9];  const float* bo  = (const float*)d_in[10];
  const float* Wcq = (const float*)d_in[11]; const float* bcq = (const float*)d_in[12];
  const float* Wck = (const float*)d_in[13]; const float* bck = (const float*)d_in[14];
  const float* Wcv = (const float*)d_in[15]; const float* bcv = (const float*)d_in[16];
  const float* Wd  = (const float*)d_in[17]; const float* bd  = (const float*)d_in[18];
  float* out = (float*)d_out;

  const size_t BT = (size_t)Bsz * Tn;          // 4096
  const size_t nQ = BT * Dn;                   // 8.39M
  const size_t nL = BT * Hn * Ln;              // 4.19M
  const size_t nW = (size_t)Dn * Dn;
  float* ws    = (float*)d_ws;
  float* Q     = ws;
  float* Kb    = Q + nQ;
  float* V     = Kb + nQ;
  float* olatT = V + nQ;
  u16* qlat  = (u16*)(olatT + nL);
  u16* klat  = qlat + nL;
  u16* vlatT = klat + nL;
  u16* xh    = vlatT + nL;
  u16* xl    = xh + nQ;
  u16* wth   = xl + nQ;
  u16* wtl   = wth + nW;

  dim3 blk(256);
  const int M = (int)BT;
  dim3 gg(Dn / 128, M / 128);
  dim3 gt(Dn / 32, Dn / 32);
  int nblkA = (int)(nQ / 8);

  split_permute<<<(nblkA + 255) / 256, blk, 0, stream>>>(x, xh, xl, nblkA, Dn);
  transpose_split<<<gt, blk, 0, stream>>>(Wq, wth, wtl, Dn, Dn);
  gemm_bf16x3<<<gg, blk, 0, stream>>>(xh, xl, wth, wtl, bq, Q, M, Dn, Dn);
  transpose_split<<<gt, blk, 0, stream>>>(Wk, wth, wtl, Dn, Dn);
  gemm_bf16x3<<<gg, blk, 0, stream>>>(xh, xl, wth, wtl, bk, Kb, M, Dn, Dn);
  transpose_split<<<gt, blk, 0, stream>>>(Wv, wth, wtl, Dn, Dn);
  gemm_bf16x3<<<gg, blk, 0, stream>>>(xh, xl, wth, wtl, bv, V, M, Dn, Dn);

  dim3 gc(Tn / 64, Bsz * Hn);
  compress_qk<<<gc, blk, 0, stream>>>(Q,  Wcq, bcq, freqs, qlat);
  compress_qk<<<gc, blk, 0, stream>>>(Kb, Wck, bck, freqs, klat);
  compress_v<<<gc, blk, 0, stream>>>(V, Wcv, bcv, vlatT);

  dim3 ga(Tn / 128, Bsz * Hn);
  attn_mfma<<<ga, blk, 0, stream>>>(qlat, klat, vlatT, olatT);

  decompress_split<<<gc, blk, 0, stream>>>(olatT, Wd, bd, xh, xl);
  transpose_split<<<gt, blk, 0, stream>>>(Wo, wth, wtl, Dn, Dn);
  gemm_bf16x3<<<gg, blk, 0, stream>>>(xh, xl, wth, wtl, bo, out, M, Dn, Dn);
}

// Round 4
// 645.058 us; speedup vs baseline: 6.8408x; 1.0695x over previous
//
#include <hip/hip_runtime.h>
#include <hip/hip_bf16.h>

static constexpr int Bsz = 2;
static constexpr int Tn  = 2048;
static constexpr int Dn  = 2048;
static constexpr int Hn  = 16;
static constexpr int Ln  = 64;
static constexpr int Hd  = 128;
static constexpr float SL2E = 0.125f * 1.44269504088896f;  // SCALE * log2(e)

typedef short short8 __attribute__((ext_vector_type(8)));
typedef float f32x4 __attribute__((ext_vector_type(4)));
typedef unsigned short ushort8 __attribute__((ext_vector_type(8)));
typedef unsigned short ushort4v __attribute__((ext_vector_type(4)));
typedef unsigned short u16;

__device__ inline unsigned short bf_rne(float f) {
  union { float f; unsigned u; } x; x.f = f;
  unsigned r = x.u + 0x7fffu + ((x.u >> 16) & 1u);
  return (unsigned short)(r >> 16);
}
__device__ inline float bf_to_f(unsigned short h) {
  union { unsigned u; float f; } x; x.u = ((unsigned)h) << 16;
  return x.f;
}

#define GL(g, l) __builtin_amdgcn_global_load_lds(                     \
    (const __attribute__((address_space(1))) void*)(g),                \
    (__attribute__((address_space(3))) void*)(l), 16, 0, 0)

// ---------- split fp32 -> bf16 hi/lo with per-32 K-window permutation ------
__global__ void split_permute(const float* __restrict__ A,
                              unsigned short* __restrict__ Oh,
                              unsigned short* __restrict__ Ol,
                              int nblk, int Kd) {
  int b = blockIdx.x * 256 + threadIdx.x;
  if (b >= nblk) return;
  int perRow = Kd >> 3;
  int m = b / perRow, gb = b - m * perRow;
  int w = gb >> 2, g = gb & 3;
  const float* src = A + (size_t)m * Kd + (w << 5) + (g << 2);
  float4 v0 = *(const float4*)src;
  float4 v1 = *(const float4*)(src + 16);
  float e[8] = {v0.x, v0.y, v0.z, v0.w, v1.x, v1.y, v1.z, v1.w};
  ushort8 hi, lo;
#pragma unroll
  for (int j = 0; j < 8; ++j) {
    unsigned short h = bf_rne(e[j]);
    hi[j] = h;
    lo[j] = bf_rne(e[j] - bf_to_f(h));
  }
  *(ushort8*)(Oh + (size_t)b * 8) = hi;
  *(ushort8*)(Ol + (size_t)b * 8) = lo;
}

// ---------- transpose W[K][N] -> WT[N][K] bf16 hi/lo, K-permuted -----------
__global__ __launch_bounds__(256) void transpose_split(
    const float* __restrict__ W, unsigned short* __restrict__ Th,
    unsigned short* __restrict__ Tl, int Kd, int Nd) {
  __shared__ float t[32][33];
  int k0 = blockIdx.x * 32, n0 = blockIdx.y * 32;
  int i = threadIdx.x;
  {
    int kk = i >> 3, nn = (i & 7) << 2;
    float4 v = *(const float4*)&W[(size_t)(k0 + kk) * Nd + n0 + nn];
    t[kk][nn] = v.x; t[kk][nn + 1] = v.y; t[kk][nn + 2] = v.z; t[kk][nn + 3] = v.w;
  }
  __syncthreads();
  int n = i >> 3, t2 = i & 7;
  int g = t2 >> 1, h = t2 & 1;
  int kbase = h * 16 + g * 4;
  ushort4v hi, lo;
#pragma unroll
  for (int j = 0; j < 4; ++j) {
    float f = t[kbase + j][n];
    unsigned short hh = bf_rne(f);
    hi[j] = hh;
    lo[j] = bf_rne(f - bf_to_f(hh));
  }
  size_t off = (size_t)(n0 + n) * Kd + k0 + t2 * 4;
  *(ushort4v*)(Th + off) = hi;
  *(ushort4v*)(Tl + off) = lo;
}

// ---------- generic 64x64-tile fp32 fold GEMM: C = A[64xk?][128] @ B[128][64]
__global__ __launch_bounds__(256) void fold64(
    const float* __restrict__ A, int lda, int a_bx, int a_by,
    const float* __restrict__ B, int ldb, int b_bx, int b_by,
    float* __restrict__ C, int ldc, int c_bx, int c_by) {
  __shared__ float a_lds[64][132];
  __shared__ float b_lds[128][64];
  const int bx = blockIdx.x, by = blockIdx.y, tid = threadIdx.x;
  A += (size_t)bx * a_bx + (size_t)by * a_by;
  B += (size_t)bx * b_bx + (size_t)by * b_by;
  C += (size_t)bx * c_bx + (size_t)by * c_by;
  for (int i = tid; i < 64 * 32; i += 256) {
    int r = i >> 5, c4 = (i & 31) << 2;
    *(float4*)&a_lds[r][c4] = *(const float4*)&A[(size_t)r * lda + c4];
  }
  for (int i = tid; i < 128 * 16; i += 256) {
    int r = i >> 4, c4 = (i & 15) << 2;
    *(float4*)&b_lds[r][c4] = *(const float4*)&B[(size_t)r * ldb + c4];
  }
  __syncthreads();
  const int r = tid >> 2, l0 = (tid & 3) << 4;
  float acc[16] = {};
  for (int k = 0; k < 128; ++k) {
    float av = a_lds[r][k];
    const float* bp = &b_lds[k][l0];
#pragma unroll
    for (int j = 0; j < 16; ++j) acc[j] += av * bp[j];
  }
#pragma unroll
  for (int j4 = 0; j4 < 4; ++j4)
    *(float4*)&C[(size_t)r * ldc + l0 + j4 * 4] = *(float4*)&acc[j4 * 4];
}

// ---------- folded biases ---------------------------------------------------
__global__ void bias_prep(const float* __restrict__ bv, const float* __restrict__ Wcv,
                          const float* __restrict__ bcv, const float* __restrict__ bd,
                          const float* __restrict__ Wo, const float* __restrict__ bo,
                          float* __restrict__ bias_vf, float* __restrict__ bias_out) {
  int idx = blockIdx.x * 256 + threadIdx.x;
  if (idx < 1024) {
    int h = idx >> 6, l = idx & 63;
    float s = bcv[l];
    for (int j = 0; j < 128; ++j) s += bv[h * 128 + j] * Wcv[j * 64 + l];
    bias_vf[idx] = s;
  } else if (idx < 3072) {
    int n = idx - 1024;
    float s = bo[n];
    for (int k = 0; k < 2048; ++k) s += bd[k & 127] * Wo[(size_t)k * 2048 + n];
    bias_out[n] = s;
  }
}

// ---------- fused QKV GEMM: N=5120 concat [Wq|Wk|Wvfold], bf16x3 -----------
__global__ __launch_bounds__(256) void gemm_qkv(
    const unsigned short* __restrict__ Ah, const unsigned short* __restrict__ Al,
    const unsigned short* __restrict__ Bh, const unsigned short* __restrict__ Bl,
    float* __restrict__ cQ, float* __restrict__ cK, float* __restrict__ cV,
    const float* __restrict__ bq, const float* __restrict__ bk,
    const float* __restrict__ bvf, int K) {
  __shared__ unsigned short s[4][128 * 32];
  const int tid = threadIdx.x;
  const int lane = tid & 63;
  const int w = tid >> 6, wr = w >> 1, wc = w & 1;
  const int row0 = blockIdx.y * 128, col0 = blockIdx.x * 128;

  const int sr = tid >> 2, sq = tid & 3;
  const int sg = sq ^ ((sr >> 1) & 3);
  const size_t aoff0 = (size_t)(row0 + sr) * K + sg * 8;
  const size_t aoff1 = (size_t)(row0 + sr + 64) * K + sg * 8;
  const size_t boff0 = (size_t)(col0 + sr) * K + sg * 8;
  const size_t boff1 = (size_t)(col0 + sr + 64) * K + sg * 8;
  const int ldst0 = tid * 16, ldst1 = (tid + 256) * 16;

  f32x4 acc[4][4];
#pragma unroll
  for (int i2 = 0; i2 < 4; ++i2)
#pragma unroll
    for (int j2 = 0; j2 < 4; ++j2) acc[i2][j2] = (f32x4){0.f, 0.f, 0.f, 0.f};

  int fa[4], fb[4];
#pragma unroll
  for (int mi = 0; mi < 4; ++mi) {
    int ra = wr * 64 + mi * 16 + (lane & 15);
    fa[mi] = ra * 64 + (((lane >> 4) ^ ((ra >> 1) & 3)) << 4);
    int rb = wc * 64 + mi * 16 + (lane & 15);
    fb[mi] = rb * 64 + (((lane >> 4) ^ ((rb >> 1) & 3)) << 4);
  }

  for (int k0 = 0; k0 < K; k0 += 32) {
    __syncthreads();
    GL(Ah + aoff0 + k0, (char*)&s[0][0] + ldst0);
    GL(Ah + aoff1 + k0, (char*)&s[0][0] + ldst1);
    GL(Al + aoff0 + k0, (char*)&s[1][0] + ldst0);
    GL(Al + aoff1 + k0, (char*)&s[1][0] + ldst1);
    GL(Bh + boff0 + k0, (char*)&s[2][0] + ldst0);
    GL(Bh + boff1 + k0, (char*)&s[2][0] + ldst1);
    GL(Bl + boff0 + k0, (char*)&s[3][0] + ldst0);
    GL(Bl + boff1 + k0, (char*)&s[3][0] + ldst1);
    __syncthreads();
    short8 ah[4], al[4], bh[4], bl[4];
#pragma unroll
    for (int mi = 0; mi < 4; ++mi) {
      ah[mi] = *(const short8*)((const char*)&s[0][0] + fa[mi]);
      al[mi] = *(const short8*)((const char*)&s[1][0] + fa[mi]);
      bh[mi] = *(const short8*)((const char*)&s[2][0] + fb[mi]);
      bl[mi] = *(const short8*)((const char*)&s[3][0] + fb[mi]);
    }
#pragma unroll
    for (int mi = 0; mi < 4; ++mi)
#pragma unroll
      for (int ni = 0; ni < 4; ++ni) {
        acc[mi][ni] = __builtin_amdgcn_mfma_f32_16x16x32_bf16(ah[mi], bh[ni], acc[mi][ni], 0, 0, 0);
        acc[mi][ni] = __builtin_amdgcn_mfma_f32_16x16x32_bf16(ah[mi], bl[ni], acc[mi][ni], 0, 0, 0);
        acc[mi][ni] = __builtin_amdgcn_mfma_f32_16x16x32_bf16(al[mi], bh[ni], acc[mi][ni], 0, 0, 0);
      }
  }
  float* Cp; const float* bp; int ldc, cl0;
  if (col0 < 2048)      { Cp = cQ; bp = bq;  ldc = 2048; cl0 = col0; }
  else if (col0 < 4096) { Cp = cK; bp = bk;  ldc = 2048; cl0 = col0 - 2048; }
  else                  { Cp = cV; bp = bvf; ldc = 1024; cl0 = col0 - 4096; }
#pragma unroll
  for (int ni = 0; ni < 4; ++ni) {
    int c = cl0 + wc * 64 + ni * 16 + (lane & 15);
    float bias = bp[c];
#pragma unroll
    for (int mi = 0; mi < 4; ++mi) {
      int rr = row0 + wr * 64 + mi * 16 + ((lane >> 4) << 2);
#pragma unroll
      for (int r = 0; r < 4; ++r)
        Cp[(size_t)(rr + r) * ldc + c] = acc[mi][ni][r] + bias;
    }
  }
}

// ---------- bf16x3 MFMA GEMM (final out-projection) ------------------------
__global__ __launch_bounds__(256) void gemm_bf16x3(
    const unsigned short* __restrict__ Ah, const unsigned short* __restrict__ Al,
    const unsigned short* __restrict__ Bh, const unsigned short* __restrict__ Bl,
    const float* __restrict__ bias, float* __restrict__ C,
    int M, int N, int K) {
  __shared__ unsigned short s[4][128 * 32];
  const int tid = threadIdx.x;
  const int lane = tid & 63;
  const int w = tid >> 6, wr = w >> 1, wc = w & 1;
  const int row0 = blockIdx.y * 128, col0 = blockIdx.x * 128;

  const int sr = tid >> 2, sq = tid & 3;
  const int sg = sq ^ ((sr >> 1) & 3);
  const size_t aoff0 = (size_t)(row0 + sr) * K + sg * 8;
  const size_t aoff1 = (size_t)(row0 + sr + 64) * K + sg * 8;
  const size_t boff0 = (size_t)(col0 + sr) * K + sg * 8;
  const size_t boff1 = (size_t)(col0 + sr + 64) * K + sg * 8;
  const int ldst0 = tid * 16, ldst1 = (tid + 256) * 16;

  f32x4 acc[4][4];
#pragma unroll
  for (int i2 = 0; i2 < 4; ++i2)
#pragma unroll
    for (int j2 = 0; j2 < 4; ++j2) acc[i2][j2] = (f32x4){0.f, 0.f, 0.f, 0.f};

  int fa[4], fb[4];
#pragma unroll
  for (int mi = 0; mi < 4; ++mi) {
    int ra = wr * 64 + mi * 16 + (lane & 15);
    fa[mi] = ra * 64 + (((lane >> 4) ^ ((ra >> 1) & 3)) << 4);
    int rb = wc * 64 + mi * 16 + (lane & 15);
    fb[mi] = rb * 64 + (((lane >> 4) ^ ((rb >> 1) & 3)) << 4);
  }

  for (int k0 = 0; k0 < K; k0 += 32) {
    __syncthreads();
    GL(Ah + aoff0 + k0, (char*)&s[0][0] + ldst0);
    GL(Ah + aoff1 + k0, (char*)&s[0][0] + ldst1);
    GL(Al + aoff0 + k0, (char*)&s[1][0] + ldst0);
    GL(Al + aoff1 + k0, (char*)&s[1][0] + ldst1);
    GL(Bh + boff0 + k0, (char*)&s[2][0] + ldst0);
    GL(Bh + boff1 + k0, (char*)&s[2][0] + ldst1);
    GL(Bl + boff0 + k0, (char*)&s[3][0] + ldst0);
    GL(Bl + boff1 + k0, (char*)&s[3][0] + ldst1);
    __syncthreads();
    short8 ah[4], al[4], bh[4], bl[4];
#pragma unroll
    for (int mi = 0; mi < 4; ++mi) {
      ah[mi] = *(const short8*)((const char*)&s[0][0] + fa[mi]);
      al[mi] = *(const short8*)((const char*)&s[1][0] + fa[mi]);
      bh[mi] = *(const short8*)((const char*)&s[2][0] + fb[mi]);
      bl[mi] = *(const short8*)((const char*)&s[3][0] + fb[mi]);
    }
#pragma unroll
    for (int mi = 0; mi < 4; ++mi)
#pragma unroll
      for (int ni = 0; ni < 4; ++ni) {
        acc[mi][ni] = __builtin_amdgcn_mfma_f32_16x16x32_bf16(ah[mi], bh[ni], acc[mi][ni], 0, 0, 0);
        acc[mi][ni] = __builtin_amdgcn_mfma_f32_16x16x32_bf16(ah[mi], bl[ni], acc[mi][ni], 0, 0, 0);
        acc[mi][ni] = __builtin_amdgcn_mfma_f32_16x16x32_bf16(al[mi], bh[ni], acc[mi][ni], 0, 0, 0);
      }
  }
#pragma unroll
  for (int ni = 0; ni < 4; ++ni) {
    int c = col0 + wc * 64 + ni * 16 + (lane & 15);
    float bv = bias[c];
#pragma unroll
    for (int mi = 0; mi < 4; ++mi) {
      int rr = row0 + wr * 64 + mi * 16 + ((lane >> 4) << 2);
#pragma unroll
      for (int r = 0; r < 4; ++r)
        C[(size_t)(rr + r) * N + c] = acc[mi][ni][r] + bv;
    }
  }
}

// ---------- fused RoPE + latent compression for Q/K ------------------------
__global__ __launch_bounds__(256) void compress_qk(
    const float* __restrict__ src, const float* __restrict__ Wc,
    const float* __restrict__ bc, const float* __restrict__ freqs,
    u16* __restrict__ dst) {
  __shared__ float q_lds[64][132];
  __shared__ float w_lds[128 * 64];
  const int tid = threadIdx.x;
  const int t0 = blockIdx.x * 64;
  const int bh = blockIdx.y, b = bh >> 4, h = bh & 15;
  for (int i = tid; i < 2048; i += 256)
    ((float4*)w_lds)[i] = ((const float4*)Wc)[i];
  const int r = tid >> 2, seg = tid & 3;
  const float* qp = src + ((size_t)(b * Tn + t0 + r)) * Dn + h * 128 + seg * 32;
  const float* fp = freqs + (size_t)(t0 + r) * 64 + seg * 16;
  float fr[16];
#pragma unroll
  for (int j = 0; j < 4; ++j) *(float4*)&fr[4 * j] = ((const float4*)fp)[j];
#pragma unroll
  for (int j = 0; j < 8; ++j) {
    float4 v = ((const float4*)qp)[j];
    float s0, c0, s1, c1;
    sincosf(fr[2 * j], &s0, &c0);
    sincosf(fr[2 * j + 1], &s1, &c1);
    q_lds[r][seg * 32 + 4 * j + 0] = v.x * c0 - v.y * s0;
    q_lds[r][seg * 32 + 4 * j + 1] = v.x * s0 + v.y * c0;
    q_lds[r][seg * 32 + 4 * j + 2] = v.z * c1 - v.w * s1;
    q_lds[r][seg * 32 + 4 * j + 3] = v.z * s1 + v.w * c1;
  }
  __syncthreads();
  const int l0 = seg * 16;
  float acc[16];
#pragma unroll
  for (int i = 0; i < 16; ++i) acc[i] = bc[l0 + i];
  for (int k = 0; k < 128; ++k) {
    float qv = q_lds[r][k];
    const float* wr = &w_lds[k * 64 + l0];
#pragma unroll
    for (int i = 0; i < 16; ++i) acc[i] += qv * wr[i];
  }
  const int w32 = l0 >> 5, h4 = (l0 >> 4) & 1;
  u16* op = dst + ((size_t)bh * Tn + t0 + r) * 64 + w32 * 32 + h4 * 4;
#pragma unroll
  for (int g = 0; g < 4; ++g) {
    ushort4v u;
#pragma unroll
    for (int q = 0; q < 4; ++q) u[q] = bf_rne(acc[g * 4 + q]);
    *(ushort4v*)(op + g * 8) = u;
  }
}

// ---------- transpose v_lat [B*T][1024] -> vlatT [bh][64][T-perm] bf16 -----
__global__ __launch_bounds__(256) void transpose_v(
    const float* __restrict__ vlat, u16* __restrict__ vlatT) {
  __shared__ u16 o_lds[64][64];
  const int tid = threadIdx.x;
  const int t0 = blockIdx.x * 64;
  const int bh = blockIdx.y, b = bh >> 4, h = bh & 15;
  const int tt = tid >> 2, lseg = tid & 3;
  const float* vp = vlat + (size_t)(b * Tn + t0 + tt) * 1024 + h * 64 + lseg * 16;
#pragma unroll
  for (int g = 0; g < 4; ++g) {
    float4 v = ((const float4*)vp)[g];
    ushort4v u = {bf_rne(v.x), bf_rne(v.y), bf_rne(v.z), bf_rne(v.w)};
    *(ushort4v*)&o_lds[tt][lseg * 16 + ((g ^ (tt & 3)) << 2)] = u;
  }
  __syncthreads();
  const int lat = tid >> 2, tseg = tid & 3;
  const int tw = tseg >> 1, h4 = tseg & 1;
  u16 vals[16];
#pragma unroll
  for (int i = 0; i < 16; ++i)
    vals[i] = o_lds[tseg * 16 + i][lat ^ ((i & 3) << 2)];
  u16* dp = vlatT + ((size_t)bh * 64 + lat) * Tn + t0 + tw * 32 + h4 * 4;
#pragma unroll
  for (int g = 0; g < 4; ++g) {
    ushort4v u = {vals[g * 4 + 0], vals[g * 4 + 1], vals[g * 4 + 2], vals[g * 4 + 3]};
    *(ushort4v*)(dp + g * 8) = u;
  }
}

// ---------- MFMA flash attention (latent dim 64, causal) -------------------
__global__ __launch_bounds__(256) void attn_mfma(
    const u16* __restrict__ qlat, const u16* __restrict__ klat,
    const u16* __restrict__ vlatT, float* __restrict__ olatT) {
  __shared__ u16 Ks[64 * 72];
  __shared__ u16 Vs[64 * 72];
  const int tid = threadIdx.x;
  const int lane = tid & 63;
  const int w = tid >> 6;
  const int bh = blockIdx.y;
  const int q0 = (int)(gridDim.x - 1 - blockIdx.x) * 128;
  const int qw = q0 + w * 32;
  const u16* ql = qlat + (size_t)bh * Tn * 64;
  const u16* kl = klat + (size_t)bh * Tn * 64;
  const u16* vt = vlatT + (size_t)bh * 64 * Tn;
  float* ot = olatT + (size_t)bh * 64 * Tn;
  const int l15 = lane & 15, lg = lane >> 4;

  short8 qf[2][2];
#pragma unroll
  for (int nf = 0; nf < 2; ++nf)
#pragma unroll
    for (int ks = 0; ks < 2; ++ks)
      qf[nf][ks] = *(const short8*)(ql + (size_t)(qw + nf * 16 + l15) * 64 + (ks * 4 + lg) * 8);

  f32x4 accO[4][2];
#pragma unroll
  for (int mi = 0; mi < 4; ++mi)
#pragma unroll
    for (int nf = 0; nf < 2; ++nf) accO[mi][nf] = (f32x4){0.f, 0.f, 0.f, 0.f};
  float mrow[2] = {-1e30f, -1e30f}, lrow[2] = {0.f, 0.f};

  const int srow = tid >> 2, spair = tid & 3;
  u16* ksw = &Ks[srow * 72 + spair * 16];
  u16* vsw = &Vs[srow * 72 + spair * 16];
  const u16* kgp = kl + (size_t)srow * 64 + spair * 16;
  const u16* vgp = vt + (size_t)srow * Tn + spair * 16;

  const int ntiles = q0 / 64 + 2;
  for (int kt = 0; kt < ntiles; ++kt) {
    const int k0 = kt * 64;
    __syncthreads();
    *(short8*)ksw       = *(const short8*)(kgp + (size_t)k0 * 64);
    *(short8*)(ksw + 8) = *(const short8*)(kgp + (size_t)k0 * 64 + 8);
    *(short8*)vsw       = *(const short8*)(vgp + k0);
    *(short8*)(vsw + 8) = *(const short8*)(vgp + k0 + 8);
    __syncthreads();
    if (k0 > qw + 31) continue;

    f32x4 s4[4][2];
#pragma unroll
    for (int mi = 0; mi < 4; ++mi) {
      s4[mi][0] = (f32x4){0.f, 0.f, 0.f, 0.f};
      s4[mi][1] = (f32x4){0.f, 0.f, 0.f, 0.f};
    }
#pragma unroll
    for (int ks = 0; ks < 2; ++ks) {
      short8 kf[4];
#pragma unroll
      for (int mi = 0; mi < 4; ++mi)
        kf[mi] = *(const short8*)&Ks[(mi * 16 + l15) * 72 + (ks * 4 + lg) * 8];
#pragma unroll
      for (int mi = 0; mi < 4; ++mi) {
        s4[mi][0] = __builtin_amdgcn_mfma_f32_16x16x32_bf16(kf[mi], qf[0][ks], s4[mi][0], 0, 0, 0);
        s4[mi][1] = __builtin_amdgcn_mfma_f32_16x16x32_bf16(kf[mi], qf[1][ks], s4[mi][1], 0, 0, 0);
      }
    }
    short8 pf[2][2];
#pragma unroll
    for (int nf = 0; nf < 2; ++nf) {
      const int qidx = qw + nf * 16 + l15;
      float p[4][4];
      float tmax = -1e30f;
#pragma unroll
      for (int mi = 0; mi < 4; ++mi)
#pragma unroll
        for (int rr = 0; rr < 4; ++rr) {
          int kv = k0 + mi * 16 + lg * 4 + rr;
          float v = s4[mi][nf][rr] * SL2E;
          if (kv > qidx) v = -1e30f;
          p[mi][rr] = v;
          tmax = fmaxf(tmax, v);
        }
      tmax = fmaxf(tmax, __shfl_xor(tmax, 16));
      tmax = fmaxf(tmax, __shfl_xor(tmax, 32));
      float mnew = fmaxf(mrow[nf], tmax);
      float alpha = exp2f(mrow[nf] - mnew);
      mrow[nf] = mnew;
      float psum = 0.f;
#pragma unroll
      for (int mi = 0; mi < 4; ++mi)
#pragma unroll
        for (int rr = 0; rr < 4; ++rr) {
          float e = exp2f(p[mi][rr] - mnew);
          unsigned hb = __float_as_uint(e) & 0xffff0000u;
          psum += __uint_as_float(hb);
          p[mi][rr] = __uint_as_float(hb);
        }
      psum += __shfl_xor(psum, 16);
      psum += __shfl_xor(psum, 32);
      lrow[nf] = lrow[nf] * alpha + psum;
#pragma unroll
      for (int mi = 0; mi < 4; ++mi)
#pragma unroll
        for (int rr = 0; rr < 4; ++rr) accO[mi][nf][rr] *= alpha;
#pragma unroll
      for (int ks = 0; ks < 2; ++ks) {
        short8 f;
#pragma unroll
        for (int rr = 0; rr < 4; ++rr) {
          f[rr]     = (short)(__float_as_uint(p[2 * ks][rr]) >> 16);
          f[4 + rr] = (short)(__float_as_uint(p[2 * ks + 1][rr]) >> 16);
        }
        pf[nf][ks] = f;
      }
    }
#pragma unroll
    for (int ks = 0; ks < 2; ++ks) {
      short8 vf[4];
#pragma unroll
      for (int mi = 0; mi < 4; ++mi)
        vf[mi] = *(const short8*)&Vs[(mi * 16 + l15) * 72 + (ks * 4 + lg) * 8];
#pragma unroll
      for (int mi = 0; mi < 4; ++mi) {
        accO[mi][0] = __builtin_amdgcn_mfma_f32_16x16x32_bf16(vf[mi], pf[0][ks], accO[mi][0], 0, 0, 0);
        accO[mi][1] = __builtin_amdgcn_mfma_f32_16x16x32_bf16(vf[mi], pf[1][ks], accO[mi][1], 0, 0, 0);
      }
    }
  }
#pragma unroll
  for (int nf = 0; nf < 2; ++nf) {
    float inv = 1.f / lrow[nf];
    int q = qw + nf * 16 + l15;
#pragma unroll
    for (int mi = 0; mi < 4; ++mi)
#pragma unroll
      for (int rr = 0; rr < 4; ++rr)
        ot[(size_t)(mi * 16 + lg * 4 + rr) * Tn + q] = accO[mi][nf][rr] * inv;
  }
}

// ---------- olatT [bh][64][T] fp32 -> oh/ol [B*T][1024] hi/lo K-permuted ---
__global__ __launch_bounds__(256) void o_split(
    const float* __restrict__ olatT, u16* __restrict__ oh, u16* __restrict__ ol) {
  __shared__ u16 hs[64][64], ls[64][64];
  const int tid = threadIdx.x;
  const int q0 = blockIdx.x * 64;
  const int bh = blockIdx.y, b = bh >> 4, h = bh & 15;
  const int lat = tid >> 2, qseg = tid & 3;
  const float* op = olatT + ((size_t)bh * 64 + lat) * Tn + q0 + qseg * 16;
#pragma unroll
  for (int g = 0; g < 4; ++g) {
    float4 v = ((const float4*)op)[g];
    float e[4] = {v.x, v.y, v.z, v.w};
    ushort4v uh, ul;
#pragma unroll
    for (int q = 0; q < 4; ++q) {
      u16 hb = bf_rne(e[q]);
      uh[q] = hb;
      ul[q] = bf_rne(e[q] - bf_to_f(hb));
    }
    int sc = qseg * 16 + ((g ^ (lat & 3)) << 2);
    *(ushort4v*)&hs[lat][sc] = uh;
    *(ushort4v*)&ls[lat][sc] = ul;
  }
  __syncthreads();
  const int qq = tid >> 2, lseg = tid & 3;
  u16 vh[16], vl[16];
#pragma unroll
  for (int i = 0; i < 16; ++i) {
    vh[i] = hs[lseg * 16 + i][qq ^ ((i & 3) << 2)];
    vl[i] = ls[lseg * 16 + i][qq ^ ((i & 3) << 2)];
  }
  size_t rb = (size_t)(b * Tn + q0 + qq) * 1024 + h * 64 + (lseg >> 1) * 32 + (lseg & 1) * 4;
#pragma unroll
  for (int g = 0; g < 4; ++g) {
    ushort4v uh = {vh[g * 4], vh[g * 4 + 1], vh[g * 4 + 2], vh[g * 4 + 3]};
    ushort4v ul = {vl[g * 4], vl[g * 4 + 1], vl[g * 4 + 2], vl[g * 4 + 3]};
    *(ushort4v*)(oh + rb + g * 8) = uh;
    *(ushort4v*)(ol + rb + g * 8) = ul;
  }
}

// ---------------------------------------------------------------------------
extern "C" void kernel_launch(void* const* d_in, const int* in_sizes, int n_in,
                              void* d_out, int out_size, void* d_ws, size_t ws_size,
                              hipStream_t stream) {
  const float* x     = (const float*)d_in[0];
  const float* freqs = (const float*)d_in[1];
  const float* Wq  = (const float*)d_in[3];  const float* bq  = (const float*)d_in[4];
  const float* Wk  = (const float*)d_in[5];  const float* bk  = (const float*)d_in[6];
  const float* Wv  = (const float*)d_in[7];  const float* bv  = (const float*)d_in[8];
  const float* Wo  = (const float*)d_in[9];  const float* bo  = (const float*)d_in[10];
  const float* Wcq = (const float*)d_in[11]; const float* bcq = (const float*)d_in[12];
  const float* Wck = (const float*)d_in[13]; const float* bck = (const float*)d_in[14];
  const float* Wcv = (const float*)d_in[15]; const float* bcv = (const float*)d_in[16];
  const float* Wd  = (const float*)d_in[17]; const float* bd  = (const float*)d_in[18];
  float* out = (float*)d_out;

  const size_t BT = (size_t)Bsz * Tn;          // 4096
  const size_t nQ = BT * Dn;                   // 8.39M
  const size_t nL = BT * Hn * Ln;              // 4.19M
  const size_t nWT = (size_t)5120 * 2048;      // 10.49M

  char* ws = (char*)d_ws;
  // region 1 (dead after gemm_qkv):
  u16* xh  = (u16*)ws;
  u16* xl  = xh + nQ;
  u16* WTh = xl + nQ;
  u16* WTl = WTh + nWT;
  float* Wvf = (float*)(WTl + nWT);            // [2048][1024]
  char* r2 = (char*)(Wvf + (size_t)2048 * 1024);
  // region 2:
  float* Q    = (float*)r2;
  float* Kb   = Q + nQ;
  float* vlat = Kb + nQ;                        // [4096][1024]
  float* bias_vf  = vlat + (size_t)4096 * 1024; // 1024
  float* bias_out = bias_vf + 1024;             // 2048
  // region 1 reuse (after gemm_qkv):
  u16* qlat  = (u16*)ws;
  u16* klat  = qlat + nL;
  u16* vlatT = klat + nL;
  float* olatT = (float*)(vlatT + nL);
  u16* oh = (u16*)(olatT + nL);
  u16* ol = oh + (size_t)4096 * 1024;
  float* Wdo = (float*)(ol + (size_t)4096 * 1024);  // [1024][2048]
  u16* WdoTh = (u16*)(Wdo + (size_t)1024 * 2048);
  u16* WdoTl = WdoTh + (size_t)1024 * 2048;

  dim3 blk(256);
  int nblkA = (int)(nQ / 8);

  // stage 1: operand prep
  split_permute<<<(nblkA + 255) / 256, blk, 0, stream>>>(x, xh, xl, nblkA, Dn);
  fold64<<<dim3(32, 16), blk, 0, stream>>>(Wv, 2048, 64 * 2048, 128,
                                           Wcv, 64, 0, 0,
                                           Wvf, 1024, 64 * 1024, 64);
  transpose_split<<<dim3(64, 64), blk, 0, stream>>>(Wq, WTh, WTl, 2048, 2048);
  transpose_split<<<dim3(64, 64), blk, 0, stream>>>(Wk, WTh + (size_t)2048 * 2048,
                                                    WTl + (size_t)2048 * 2048, 2048, 2048);
  transpose_split<<<dim3(64, 32), blk, 0, stream>>>(Wvf, WTh + (size_t)4096 * 2048,
                                                    WTl + (size_t)4096 * 2048, 2048, 1024);
  bias_prep<<<12, blk, 0, stream>>>(bv, Wcv, bcv, bd, Wo, bo, bias_vf, bias_out);

  // stage 2: fused Q/K/V-latent GEMM (N = 5120)
  gemm_qkv<<<dim3(40, 32), blk, 0, stream>>>(xh, xl, WTh, WTl, Q, Kb, vlat,
                                             bq, bk, bias_vf, 2048);

  // stage 3: latent Q/K (RoPE fused) + V transpose
  dim3 gc(Tn / 64, Bsz * Hn);
  compress_qk<<<gc, blk, 0, stream>>>(Q,  Wcq, bcq, freqs, qlat);
  compress_qk<<<gc, blk, 0, stream>>>(Kb, Wck, bck, freqs, klat);
  transpose_v<<<gc, blk, 0, stream>>>(vlat, vlatT);

  // stage 4: attention
  attn_mfma<<<dim3(Tn / 128, Bsz * Hn), blk, 0, stream>>>(qlat, klat, vlatT, olatT);

  // stage 5: folded decompress+output projection
  o_split<<<gc, blk, 0, stream>>>(olatT, oh, ol);
  fold64<<<dim3(32, 16), blk, 0, stream>>>(Wd, 128, 0, 0,
                                           Wo, 2048, 64, 128 * 2048,
                                           Wdo, 2048, 64, 64 * 2048);
  transpose_split<<<dim3(32, 64), blk, 0, stream>>>(Wdo, WdoTh, WdoTl, 1024, 2048);
  gemm_bf16x3<<<dim3(16, 32), blk, 0, stream>>>(oh, ol, WdoTh, WdoTl, bias_out,
                                                out, (int)BT, 2048, 1024);
}

// Round 5
// 470.774 us; speedup vs baseline: 9.3734x; 1.3702x over previous
//
#include <hip/hip_runtime.h>
#include <hip/hip_bf16.h>

static constexpr int Bsz = 2;
static constexpr int Tn  = 2048;
static constexpr int Dn  = 2048;
static constexpr int Hn  = 16;
static constexpr int Ln  = 64;
static constexpr int Hd  = 128;
static constexpr float SL2E = 0.125f * 1.44269504088896f;  // SCALE * log2(e)

typedef short short8 __attribute__((ext_vector_type(8)));
typedef float f32x4 __attribute__((ext_vector_type(4)));
typedef unsigned short ushort8 __attribute__((ext_vector_type(8)));
typedef unsigned short ushort4v __attribute__((ext_vector_type(4)));
typedef _Float16 half8 __attribute__((ext_vector_type(8)));
typedef unsigned short u16;

__device__ inline unsigned short bf_rne(float f) {
  union { float f; unsigned u; } x; x.f = f;
  unsigned r = x.u + 0x7fffu + ((x.u >> 16) & 1u);
  return (unsigned short)(r >> 16);
}
__device__ inline float bf_to_f(unsigned short h) {
  union { unsigned u; float f; } x; x.u = ((unsigned)h) << 16;
  return x.f;
}
__device__ inline u16 f16_rne(float f) {
  _Float16 h = (_Float16)f;  // RNE
  union { _Float16 h; u16 u; } x; x.h = h;
  return x.u;
}

#define GL(g, l) __builtin_amdgcn_global_load_lds(                     \
    (const __attribute__((address_space(1))) void*)(g),                \
    (__attribute__((address_space(3))) void*)(l), 16, 0, 0)

// ---------- fp32 -> fp16 with per-32 K-window permutation ------------------
// permuted index p = g*8 + h*4 + q  <->  k = h*16 + g*4 + q
__global__ void split_h(const float* __restrict__ A, u16* __restrict__ O,
                        int nblk, int Kd) {
  int b = blockIdx.x * 256 + threadIdx.x;
  if (b >= nblk) return;
  int perRow = Kd >> 3;
  int m = b / perRow, gb = b - m * perRow;
  int w = gb >> 2, g = gb & 3;
  const float* src = A + (size_t)m * Kd + (w << 5) + (g << 2);
  float4 v0 = *(const float4*)src;
  float4 v1 = *(const float4*)(src + 16);
  float e[8] = {v0.x, v0.y, v0.z, v0.w, v1.x, v1.y, v1.z, v1.w};
  ushort8 o;
#pragma unroll
  for (int j = 0; j < 8; ++j) o[j] = f16_rne(e[j]);
  *(ushort8*)(O + (size_t)b * 8) = o;
}

// ---------- transpose W[K][N] -> WT[N][K] fp16, K-permuted -----------------
__global__ __launch_bounds__(256) void transpose_h(
    const float* __restrict__ W, u16* __restrict__ Th, int Kd, int Nd) {
  __shared__ float t[32][33];
  int k0 = blockIdx.x * 32, n0 = blockIdx.y * 32;
  int i = threadIdx.x;
  {
    int kk = i >> 3, nn = (i & 7) << 2;
    float4 v = *(const float4*)&W[(size_t)(k0 + kk) * Nd + n0 + nn];
    t[kk][nn] = v.x; t[kk][nn + 1] = v.y; t[kk][nn + 2] = v.z; t[kk][nn + 3] = v.w;
  }
  __syncthreads();
  int n = i >> 3, t2 = i & 7;
  int g = t2 >> 1, h = t2 & 1;
  int kbase = h * 16 + g * 4;
  ushort4v o;
#pragma unroll
  for (int j = 0; j < 4; ++j) o[j] = f16_rne(t[kbase + j][n]);
  *(ushort4v*)(Th + (size_t)(n0 + n) * Kd + k0 + t2 * 4) = o;
}

// ---------- generic 64x64-tile fp32 fold GEMM ------------------------------
__global__ __launch_bounds__(256) void fold64(
    const float* __restrict__ A, int lda, int a_bx, int a_by,
    const float* __restrict__ B, int ldb, int b_bx, int b_by,
    float* __restrict__ C, int ldc, int c_bx, int c_by) {
  __shared__ float a_lds[64][132];
  __shared__ float b_lds[128][64];
  const int bx = blockIdx.x, by = blockIdx.y, tid = threadIdx.x;
  A += (size_t)bx * a_bx + (size_t)by * a_by;
  B += (size_t)bx * b_bx + (size_t)by * b_by;
  C += (size_t)bx * c_bx + (size_t)by * c_by;
  for (int i = tid; i < 64 * 32; i += 256) {
    int r = i >> 5, c4 = (i & 31) << 2;
    *(float4*)&a_lds[r][c4] = *(const float4*)&A[(size_t)r * lda + c4];
  }
  for (int i = tid; i < 128 * 16; i += 256) {
    int r = i >> 4, c4 = (i & 15) << 2;
    *(float4*)&b_lds[r][c4] = *(const float4*)&B[(size_t)r * ldb + c4];
  }
  __syncthreads();
  const int r = tid >> 2, l0 = (tid & 3) << 4;
  float acc[16] = {};
  for (int k = 0; k < 128; ++k) {
    float av = a_lds[r][k];
    const float* bp = &b_lds[k][l0];
#pragma unroll
    for (int j = 0; j < 16; ++j) acc[j] += av * bp[j];
  }
#pragma unroll
  for (int j4 = 0; j4 < 4; ++j4)
    *(float4*)&C[(size_t)r * ldc + l0 + j4 * 4] = *(float4*)&acc[j4 * 4];
}

// ---------- folded biases ---------------------------------------------------
__global__ void bias_prep(const float* __restrict__ bv, const float* __restrict__ Wcv,
                          const float* __restrict__ bcv, const float* __restrict__ bd,
                          const float* __restrict__ Wo, const float* __restrict__ bo,
                          float* __restrict__ bias_vf, float* __restrict__ bias_out) {
  int idx = blockIdx.x * 256 + threadIdx.x;
  if (idx < 1024) {
    int h = idx >> 6, l = idx & 63;
    float s = bcv[l];
    for (int j = 0; j < 128; ++j) s += bv[h * 128 + j] * Wcv[j * 64 + l];
    bias_vf[idx] = s;
  } else if (idx < 3072) {
    int n = idx - 1024;
    float s = bo[n];
    for (int k = 0; k < 2048; ++k) s += bd[k & 127] * Wo[(size_t)k * 2048 + n];
    bias_out[n] = s;
  }
}

// ---------- fused QKV GEMM fp16: N=5120 concat [Wq|Wk|Wvfold] --------------
__global__ __launch_bounds__(256) void gemm_qkv(
    const u16* __restrict__ Af, const u16* __restrict__ Bf,
    float* __restrict__ cQ, float* __restrict__ cK, float* __restrict__ cV,
    const float* __restrict__ bq, const float* __restrict__ bk,
    const float* __restrict__ bvf, int K) {
  __shared__ u16 s[2][128 * 32];
  const int tid = threadIdx.x;
  const int lane = tid & 63;
  const int w = tid >> 6, wr = w >> 1, wc = w & 1;
  const int row0 = blockIdx.y * 128, col0 = blockIdx.x * 128;

  const int sr = tid >> 2, sq = tid & 3;
  const int sg = sq ^ ((sr >> 1) & 3);
  const size_t aoff0 = (size_t)(row0 + sr) * K + sg * 8;
  const size_t aoff1 = (size_t)(row0 + sr + 64) * K + sg * 8;
  const size_t boff0 = (size_t)(col0 + sr) * K + sg * 8;
  const size_t boff1 = (size_t)(col0 + sr + 64) * K + sg * 8;
  const int ldst0 = tid * 16, ldst1 = (tid + 256) * 16;

  f32x4 acc[4][4];
#pragma unroll
  for (int i2 = 0; i2 < 4; ++i2)
#pragma unroll
    for (int j2 = 0; j2 < 4; ++j2) acc[i2][j2] = (f32x4){0.f, 0.f, 0.f, 0.f};

  int fa[4], fb[4];
#pragma unroll
  for (int mi = 0; mi < 4; ++mi) {
    int ra = wr * 64 + mi * 16 + (lane & 15);
    fa[mi] = ra * 64 + (((lane >> 4) ^ ((ra >> 1) & 3)) << 4);
    int rb = wc * 64 + mi * 16 + (lane & 15);
    fb[mi] = rb * 64 + (((lane >> 4) ^ ((rb >> 1) & 3)) << 4);
  }

  for (int k0 = 0; k0 < K; k0 += 32) {
    __syncthreads();
    GL(Af + aoff0 + k0, (char*)&s[0][0] + ldst0);
    GL(Af + aoff1 + k0, (char*)&s[0][0] + ldst1);
    GL(Bf + boff0 + k0, (char*)&s[1][0] + ldst0);
    GL(Bf + boff1 + k0, (char*)&s[1][0] + ldst1);
    __syncthreads();
    half8 a[4], b[4];
#pragma unroll
    for (int mi = 0; mi < 4; ++mi) {
      a[mi] = *(const half8*)((const char*)&s[0][0] + fa[mi]);
      b[mi] = *(const half8*)((const char*)&s[1][0] + fb[mi]);
    }
#pragma unroll
    for (int mi = 0; mi < 4; ++mi)
#pragma unroll
      for (int ni = 0; ni < 4; ++ni)
        acc[mi][ni] = __builtin_amdgcn_mfma_f32_16x16x32_f16(a[mi], b[ni], acc[mi][ni], 0, 0, 0);
  }
  float* Cp; const float* bp; int ldc, cl0;
  if (col0 < 2048)      { Cp = cQ; bp = bq;  ldc = 2048; cl0 = col0; }
  else if (col0 < 4096) { Cp = cK; bp = bk;  ldc = 2048; cl0 = col0 - 2048; }
  else                  { Cp = cV; bp = bvf; ldc = 1024; cl0 = col0 - 4096; }
#pragma unroll
  for (int ni = 0; ni < 4; ++ni) {
    int c = cl0 + wc * 64 + ni * 16 + (lane & 15);
    float bias = bp[c];
#pragma unroll
    for (int mi = 0; mi < 4; ++mi) {
      int rr = row0 + wr * 64 + mi * 16 + ((lane >> 4) << 2);
#pragma unroll
      for (int r = 0; r < 4; ++r)
        Cp[(size_t)(rr + r) * ldc + c] = acc[mi][ni][r] + bias;
    }
  }
}

// ---------- fp16 MFMA GEMM (final out-projection) --------------------------
__global__ __launch_bounds__(256) void gemm_f16(
    const u16* __restrict__ Af, const u16* __restrict__ Bf,
    const float* __restrict__ bias, float* __restrict__ C,
    int M, int N, int K) {
  __shared__ u16 s[2][128 * 32];
  const int tid = threadIdx.x;
  const int lane = tid & 63;
  const int w = tid >> 6, wr = w >> 1, wc = w & 1;
  const int row0 = blockIdx.y * 128, col0 = blockIdx.x * 128;

  const int sr = tid >> 2, sq = tid & 3;
  const int sg = sq ^ ((sr >> 1) & 3);
  const size_t aoff0 = (size_t)(row0 + sr) * K + sg * 8;
  const size_t aoff1 = (size_t)(row0 + sr + 64) * K + sg * 8;
  const size_t boff0 = (size_t)(col0 + sr) * K + sg * 8;
  const size_t boff1 = (size_t)(col0 + sr + 64) * K + sg * 8;
  const int ldst0 = tid * 16, ldst1 = (tid + 256) * 16;

  f32x4 acc[4][4];
#pragma unroll
  for (int i2 = 0; i2 < 4; ++i2)
#pragma unroll
    for (int j2 = 0; j2 < 4; ++j2) acc[i2][j2] = (f32x4){0.f, 0.f, 0.f, 0.f};

  int fa[4], fb[4];
#pragma unroll
  for (int mi = 0; mi < 4; ++mi) {
    int ra = wr * 64 + mi * 16 + (lane & 15);
    fa[mi] = ra * 64 + (((lane >> 4) ^ ((ra >> 1) & 3)) << 4);
    int rb = wc * 64 + mi * 16 + (lane & 15);
    fb[mi] = rb * 64 + (((lane >> 4) ^ ((rb >> 1) & 3)) << 4);
  }

  for (int k0 = 0; k0 < K; k0 += 32) {
    __syncthreads();
    GL(Af + aoff0 + k0, (char*)&s[0][0] + ldst0);
    GL(Af + aoff1 + k0, (char*)&s[0][0] + ldst1);
    GL(Bf + boff0 + k0, (char*)&s[1][0] + ldst0);
    GL(Bf + boff1 + k0, (char*)&s[1][0] + ldst1);
    __syncthreads();
    half8 a[4], b[4];
#pragma unroll
    for (int mi = 0; mi < 4; ++mi) {
      a[mi] = *(const half8*)((const char*)&s[0][0] + fa[mi]);
      b[mi] = *(const half8*)((const char*)&s[1][0] + fb[mi]);
    }
#pragma unroll
    for (int mi = 0; mi < 4; ++mi)
#pragma unroll
      for (int ni = 0; ni < 4; ++ni)
        acc[mi][ni] = __builtin_amdgcn_mfma_f32_16x16x32_f16(a[mi], b[ni], acc[mi][ni], 0, 0, 0);
  }
#pragma unroll
  for (int ni = 0; ni < 4; ++ni) {
    int c = col0 + wc * 64 + ni * 16 + (lane & 15);
    float bv = bias[c];
#pragma unroll
    for (int mi = 0; mi < 4; ++mi) {
      int rr = row0 + wr * 64 + mi * 16 + ((lane >> 4) << 2);
#pragma unroll
      for (int r = 0; r < 4; ++r)
        C[(size_t)(rr + r) * N + c] = acc[mi][ni][r] + bv;
    }
  }
}

// ---------- fused RoPE + latent compression for Q/K ------------------------
__global__ __launch_bounds__(256) void compress_qk(
    const float* __restrict__ src, const float* __restrict__ Wc,
    const float* __restrict__ bc, const float* __restrict__ freqs,
    u16* __restrict__ dst) {
  __shared__ float q_lds[64][132];
  __shared__ float w_lds[128 * 64];
  const int tid = threadIdx.x;
  const int t0 = blockIdx.x * 64;
  const int bh = blockIdx.y, b = bh >> 4, h = bh & 15;
  for (int i = tid; i < 2048; i += 256)
    ((float4*)w_lds)[i] = ((const float4*)Wc)[i];
  const int r = tid >> 2, seg = tid & 3;
  const float* qp = src + ((size_t)(b * Tn + t0 + r)) * Dn + h * 128 + seg * 32;
  const float* fp = freqs + (size_t)(t0 + r) * 64 + seg * 16;
  float fr[16];
#pragma unroll
  for (int j = 0; j < 4; ++j) *(float4*)&fr[4 * j] = ((const float4*)fp)[j];
#pragma unroll
  for (int j = 0; j < 8; ++j) {
    float4 v = ((const float4*)qp)[j];
    float s0, c0, s1, c1;
    sincosf(fr[2 * j], &s0, &c0);
    sincosf(fr[2 * j + 1], &s1, &c1);
    q_lds[r][seg * 32 + 4 * j + 0] = v.x * c0 - v.y * s0;
    q_lds[r][seg * 32 + 4 * j + 1] = v.x * s0 + v.y * c0;
    q_lds[r][seg * 32 + 4 * j + 2] = v.z * c1 - v.w * s1;
    q_lds[r][seg * 32 + 4 * j + 3] = v.z * s1 + v.w * c1;
  }
  __syncthreads();
  const int l0 = seg * 16;
  float acc[16];
#pragma unroll
  for (int i = 0; i < 16; ++i) acc[i] = bc[l0 + i];
  for (int k = 0; k < 128; ++k) {
    float qv = q_lds[r][k];
    const float* wr = &w_lds[k * 64 + l0];
#pragma unroll
    for (int i = 0; i < 16; ++i) acc[i] += qv * wr[i];
  }
  const int w32 = l0 >> 5, h4 = (l0 >> 4) & 1;
  u16* op = dst + ((size_t)bh * Tn + t0 + r) * 64 + w32 * 32 + h4 * 4;
#pragma unroll
  for (int g = 0; g < 4; ++g) {
    ushort4v u;
#pragma unroll
    for (int q = 0; q < 4; ++q) u[q] = bf_rne(acc[g * 4 + q]);
    *(ushort4v*)(op + g * 8) = u;
  }
}

// ---------- transpose v_lat [B*T][1024] -> vlatT [bh][64][T-perm] bf16 -----
__global__ __launch_bounds__(256) void transpose_v(
    const float* __restrict__ vlat, u16* __restrict__ vlatT) {
  __shared__ u16 o_lds[64][64];
  const int tid = threadIdx.x;
  const int t0 = blockIdx.x * 64;
  const int bh = blockIdx.y, b = bh >> 4, h = bh & 15;
  const int tt = tid >> 2, lseg = tid & 3;
  const float* vp = vlat + (size_t)(b * Tn + t0 + tt) * 1024 + h * 64 + lseg * 16;
#pragma unroll
  for (int g = 0; g < 4; ++g) {
    float4 v = ((const float4*)vp)[g];
    ushort4v u = {bf_rne(v.x), bf_rne(v.y), bf_rne(v.z), bf_rne(v.w)};
    *(ushort4v*)&o_lds[tt][lseg * 16 + ((g ^ (tt & 3)) << 2)] = u;
  }
  __syncthreads();
  const int lat = tid >> 2, tseg = tid & 3;
  const int tw = tseg >> 1, h4 = tseg & 1;
  u16 vals[16];
#pragma unroll
  for (int i = 0; i < 16; ++i)
    vals[i] = o_lds[tseg * 16 + i][lat ^ ((i & 3) << 2)];
  u16* dp = vlatT + ((size_t)bh * 64 + lat) * Tn + t0 + tw * 32 + h4 * 4;
#pragma unroll
  for (int g = 0; g < 4; ++g) {
    ushort4v u = {vals[g * 4 + 0], vals[g * 4 + 1], vals[g * 4 + 2], vals[g * 4 + 3]};
    *(ushort4v*)(dp + g * 8) = u;
  }
}

// ---------- MFMA flash attention (latent dim 64, causal) -------------------
__global__ __launch_bounds__(256) void attn_mfma(
    const u16* __restrict__ qlat, const u16* __restrict__ klat,
    const u16* __restrict__ vlatT, float* __restrict__ olatT) {
  __shared__ u16 Ks[64 * 72];
  __shared__ u16 Vs[64 * 72];
  const int tid = threadIdx.x;
  const int lane = tid & 63;
  const int w = tid >> 6;
  const int bh = blockIdx.y;
  const int q0 = (int)(gridDim.x - 1 - blockIdx.x) * 128;
  const int qw = q0 + w * 32;
  const u16* ql = qlat + (size_t)bh * Tn * 64;
  const u16* kl = klat + (size_t)bh * Tn * 64;
  const u16* vt = vlatT + (size_t)bh * 64 * Tn;
  float* ot = olatT + (size_t)bh * 64 * Tn;
  const int l15 = lane & 15, lg = lane >> 4;

  short8 qf[2][2];
#pragma unroll
  for (int nf = 0; nf < 2; ++nf)
#pragma unroll
    for (int ks = 0; ks < 2; ++ks)
      qf[nf][ks] = *(const short8*)(ql + (size_t)(qw + nf * 16 + l15) * 64 + (ks * 4 + lg) * 8);

  f32x4 accO[4][2];
#pragma unroll
  for (int mi = 0; mi < 4; ++mi)
#pragma unroll
    for (int nf = 0; nf < 2; ++nf) accO[mi][nf] = (f32x4){0.f, 0.f, 0.f, 0.f};
  float mrow[2] = {-1e30f, -1e30f}, lrow[2] = {0.f, 0.f};

  const int srow = tid >> 2, spair = tid & 3;
  u16* ksw = &Ks[srow * 72 + spair * 16];
  u16* vsw = &Vs[srow * 72 + spair * 16];
  const u16* kgp = kl + (size_t)srow * 64 + spair * 16;
  const u16* vgp = vt + (size_t)srow * Tn + spair * 16;

  const int ntiles = q0 / 64 + 2;
  for (int kt = 0; kt < ntiles; ++kt) {
    const int k0 = kt * 64;
    __syncthreads();
    *(short8*)ksw       = *(const short8*)(kgp + (size_t)k0 * 64);
    *(short8*)(ksw + 8) = *(const short8*)(kgp + (size_t)k0 * 64 + 8);
    *(short8*)vsw       = *(const short8*)(vgp + k0);
    *(short8*)(vsw + 8) = *(const short8*)(vgp + k0 + 8);
    __syncthreads();
    if (k0 > qw + 31) continue;

    f32x4 s4[4][2];
#pragma unroll
    for (int mi = 0; mi < 4; ++mi) {
      s4[mi][0] = (f32x4){0.f, 0.f, 0.f, 0.f};
      s4[mi][1] = (f32x4){0.f, 0.f, 0.f, 0.f};
    }
#pragma unroll
    for (int ks = 0; ks < 2; ++ks) {
      short8 kf[4];
#pragma unroll
      for (int mi = 0; mi < 4; ++mi)
        kf[mi] = *(const short8*)&Ks[(mi * 16 + l15) * 72 + (ks * 4 + lg) * 8];
#pragma unroll
      for (int mi = 0; mi < 4; ++mi) {
        s4[mi][0] = __builtin_amdgcn_mfma_f32_16x16x32_bf16(kf[mi], qf[0][ks], s4[mi][0], 0, 0, 0);
        s4[mi][1] = __builtin_amdgcn_mfma_f32_16x16x32_bf16(kf[mi], qf[1][ks], s4[mi][1], 0, 0, 0);
      }
    }
    short8 pf[2][2];
#pragma unroll
    for (int nf = 0; nf < 2; ++nf) {
      const int qidx = qw + nf * 16 + l15;
      float p[4][4];
      float tmax = -1e30f;
#pragma unroll
      for (int mi = 0; mi < 4; ++mi)
#pragma unroll
        for (int rr = 0; rr < 4; ++rr) {
          int kv = k0 + mi * 16 + lg * 4 + rr;
          float v = s4[mi][nf][rr] * SL2E;
          if (kv > qidx) v = -1e30f;
          p[mi][rr] = v;
          tmax = fmaxf(tmax, v);
        }
      tmax = fmaxf(tmax, __shfl_xor(tmax, 16));
      tmax = fmaxf(tmax, __shfl_xor(tmax, 32));
      float mnew = fmaxf(mrow[nf], tmax);
      float alpha = exp2f(mrow[nf] - mnew);
      mrow[nf] = mnew;
      float psum = 0.f;
#pragma unroll
      for (int mi = 0; mi < 4; ++mi)
#pragma unroll
        for (int rr = 0; rr < 4; ++rr) {
          float e = exp2f(p[mi][rr] - mnew);
          unsigned hb = __float_as_uint(e) & 0xffff0000u;
          psum += __uint_as_float(hb);
          p[mi][rr] = __uint_as_float(hb);
        }
      psum += __shfl_xor(psum, 16);
      psum += __shfl_xor(psum, 32);
      lrow[nf] = lrow[nf] * alpha + psum;
#pragma unroll
      for (int mi = 0; mi < 4; ++mi)
#pragma unroll
        for (int rr = 0; rr < 4; ++rr) accO[mi][nf][rr] *= alpha;
#pragma unroll
      for (int ks = 0; ks < 2; ++ks) {
        short8 f;
#pragma unroll
        for (int rr = 0; rr < 4; ++rr) {
          f[rr]     = (short)(__float_as_uint(p[2 * ks][rr]) >> 16);
          f[4 + rr] = (short)(__float_as_uint(p[2 * ks + 1][rr]) >> 16);
        }
        pf[nf][ks] = f;
      }
    }
#pragma unroll
    for (int ks = 0; ks < 2; ++ks) {
      short8 vf[4];
#pragma unroll
      for (int mi = 0; mi < 4; ++mi)
        vf[mi] = *(const short8*)&Vs[(mi * 16 + l15) * 72 + (ks * 4 + lg) * 8];
#pragma unroll
      for (int mi = 0; mi < 4; ++mi) {
        accO[mi][0] = __builtin_amdgcn_mfma_f32_16x16x32_bf16(vf[mi], pf[0][ks], accO[mi][0], 0, 0, 0);
        accO[mi][1] = __builtin_amdgcn_mfma_f32_16x16x32_bf16(vf[mi], pf[1][ks], accO[mi][1], 0, 0, 0);
      }
    }
  }
#pragma unroll
  for (int nf = 0; nf < 2; ++nf) {
    float inv = 1.f / lrow[nf];
    int q = qw + nf * 16 + l15;
#pragma unroll
    for (int mi = 0; mi < 4; ++mi)
#pragma unroll
      for (int rr = 0; rr < 4; ++rr)
        ot[(size_t)(mi * 16 + lg * 4 + rr) * Tn + q] = accO[mi][nf][rr] * inv;
  }
}

// ---------- olatT [bh][64][T] fp32 -> oh [B*T][1024] fp16 K-permuted -------
__global__ __launch_bounds__(256) void o_split(
    const float* __restrict__ olatT, u16* __restrict__ oh) {
  __shared__ u16 hs[64][64];
  const int tid = threadIdx.x;
  const int q0 = blockIdx.x * 64;
  const int bh = blockIdx.y, b = bh >> 4, h = bh & 15;
  const int lat = tid >> 2, qseg = tid & 3;
  const float* op = olatT + ((size_t)bh * 64 + lat) * Tn + q0 + qseg * 16;
#pragma unroll
  for (int g = 0; g < 4; ++g) {
    float4 v = ((const float4*)op)[g];
    ushort4v u = {f16_rne(v.x), f16_rne(v.y), f16_rne(v.z), f16_rne(v.w)};
    *(ushort4v*)&hs[lat][qseg * 16 + ((g ^ (lat & 3)) << 2)] = u;
  }
  __syncthreads();
  const int qq = tid >> 2, lseg = tid & 3;
  u16 vh[16];
#pragma unroll
  for (int i = 0; i < 16; ++i)
    vh[i] = hs[lseg * 16 + i][qq ^ ((i & 3) << 2)];
  size_t rb = (size_t)(b * Tn + q0 + qq) * 1024 + h * 64 + (lseg >> 1) * 32 + (lseg & 1) * 4;
#pragma unroll
  for (int g = 0; g < 4; ++g) {
    ushort4v u = {vh[g * 4], vh[g * 4 + 1], vh[g * 4 + 2], vh[g * 4 + 3]};
    *(ushort4v*)(oh + rb + g * 8) = u;
  }
}

// ---------------------------------------------------------------------------
extern "C" void kernel_launch(void* const* d_in, const int* in_sizes, int n_in,
                              void* d_out, int out_size, void* d_ws, size_t ws_size,
                              hipStream_t stream) {
  const float* x     = (const float*)d_in[0];
  const float* freqs = (const float*)d_in[1];
  const float* Wq  = (const float*)d_in[3];  const float* bq  = (const float*)d_in[4];
  const float* Wk  = (const float*)d_in[5];  const float* bk  = (const float*)d_in[6];
  const float* Wv  = (const float*)d_in[7];  const float* bv  = (const float*)d_in[8];
  const float* Wo  = (const float*)d_in[9];  const float* bo  = (const float*)d_in[10];
  const float* Wcq = (const float*)d_in[11]; const float* bcq = (const float*)d_in[12];
  const float* Wck = (const float*)d_in[13]; const float* bck = (const float*)d_in[14];
  const float* Wcv = (const float*)d_in[15]; const float* bcv = (const float*)d_in[16];
  const float* Wd  = (const float*)d_in[17]; const float* bd  = (const float*)d_in[18];
  float* out = (float*)d_out;

  const size_t BT = (size_t)Bsz * Tn;          // 4096
  const size_t nQ = BT * Dn;                   // 8.39M
  const size_t nL = BT * Hn * Ln;              // 4.19M
  const size_t nWT = (size_t)5120 * 2048;      // 10.49M

  char* ws = (char*)d_ws;
  u16* xf   = (u16*)ws;                               // 16.8 MB
  u16* WTf  = xf + nQ;                                // 21.0 MB
  float* Wvf = (float*)(WTf + nWT);                   // 8.4 MB [2048][1024]
  float* Q    = Wvf + (size_t)2048 * 1024;            // 33.6 MB
  float* Kb   = Q + nQ;                               // 33.6 MB
  float* vlat = Kb + nQ;                              // 16.8 MB [4096][1024]
  float* bias_vf  = vlat + (size_t)4096 * 1024;       // 4 KB
  float* bias_out = bias_vf + 1024;                   // 8 KB
  u16* qlat  = (u16*)(bias_out + 2048);               // 8.4 MB
  u16* klat  = qlat + nL;                             // 8.4 MB
  u16* vlatT = klat + nL;                             // 8.4 MB
  float* olatT = (float*)(vlatT + nL);                // 16.8 MB
  u16* oh = (u16*)(olatT + nL);                       // 8.4 MB [4096][1024]
  float* Wdo = (float*)(oh + (size_t)4096 * 1024);    // 8.4 MB [1024][2048]
  u16* WdoT = (u16*)(Wdo + (size_t)1024 * 2048);      // 4.2 MB [2048][1024]

  dim3 blk(256);
  int nblkA = (int)(nQ / 8);

  // stage 1: operand prep (fp16 single-precision path)
  split_h<<<(nblkA + 255) / 256, blk, 0, stream>>>(x, xf, nblkA, Dn);
  fold64<<<dim3(32, 16), blk, 0, stream>>>(Wv, 2048, 64 * 2048, 128,
                                           Wcv, 64, 0, 0,
                                           Wvf, 1024, 64 * 1024, 64);
  transpose_h<<<dim3(64, 64), blk, 0, stream>>>(Wq, WTf, 2048, 2048);
  transpose_h<<<dim3(64, 64), blk, 0, stream>>>(Wk, WTf + (size_t)2048 * 2048, 2048, 2048);
  transpose_h<<<dim3(64, 32), blk, 0, stream>>>(Wvf, WTf + (size_t)4096 * 2048, 2048, 1024);
  bias_prep<<<12, blk, 0, stream>>>(bv, Wcv, bcv, bd, Wo, bo, bias_vf, bias_out);

  // stage 2: fused Q/K/V-latent GEMM (N = 5120, fp16 MFMA)
  gemm_qkv<<<dim3(40, 32), blk, 0, stream>>>(xf, WTf, Q, Kb, vlat,
                                             bq, bk, bias_vf, 2048);

  // stage 3: latent Q/K (RoPE fused) + V transpose
  dim3 gc(Tn / 64, Bsz * Hn);
  compress_qk<<<gc, blk, 0, stream>>>(Q,  Wcq, bcq, freqs, qlat);
  compress_qk<<<gc, blk, 0, stream>>>(Kb, Wck, bck, freqs, klat);
  transpose_v<<<gc, blk, 0, stream>>>(vlat, vlatT);

  // stage 4: attention
  attn_mfma<<<dim3(Tn / 128, Bsz * Hn), blk, 0, stream>>>(qlat, klat, vlatT, olatT);

  // stage 5: folded decompress+output projection (fp16 MFMA)
  o_split<<<gc, blk, 0, stream>>>(olatT, oh);
  fold64<<<dim3(32, 16), blk, 0, stream>>>(Wd, 128, 0, 0,
                                           Wo, 2048, 64, 128 * 2048,
                                           Wdo, 2048, 64, 64 * 2048);
  transpose_h<<<dim3(32, 64), blk, 0, stream>>>(Wdo, WdoT, 1024, 2048);
  gemm_f16<<<dim3(16, 32), blk, 0, stream>>>(oh, WdoT, bias_out, out, (int)BT, 2048, 1024);
}

// Round 6
// 422.821 us; speedup vs baseline: 10.4364x; 1.1134x over previous
//
#include <hip/hip_runtime.h>
#include <hip/hip_bf16.h>

static constexpr int Bsz = 2;
static constexpr int Tn  = 2048;
static constexpr int Dn  = 2048;
static constexpr int Hn  = 16;
static constexpr int Ln  = 64;
static constexpr int Hd  = 128;
static constexpr float SL2E = 0.125f * 1.44269504088896f;  // SCALE * log2(e)

typedef short short8 __attribute__((ext_vector_type(8)));
typedef float f32x4 __attribute__((ext_vector_type(4)));
typedef unsigned short ushort8 __attribute__((ext_vector_type(8)));
typedef unsigned short ushort4v __attribute__((ext_vector_type(4)));
typedef _Float16 half8 __attribute__((ext_vector_type(8)));
typedef unsigned short u16;

__device__ inline unsigned short bf_rne(float f) {
  union { float f; unsigned u; } x; x.f = f;
  unsigned r = x.u + 0x7fffu + ((x.u >> 16) & 1u);
  return (unsigned short)(r >> 16);
}
__device__ inline float bf_to_f(unsigned short h) {
  union { unsigned u; float f; } x; x.u = ((unsigned)h) << 16;
  return x.f;
}
__device__ inline u16 f16_rne(float f) {
  _Float16 h = (_Float16)f;  // RNE
  union { _Float16 h; u16 u; } x; x.h = h;
  return x.u;
}

#define GL(g, l) __builtin_amdgcn_global_load_lds(                     \
    (const __attribute__((address_space(1))) void*)(g),                \
    (__attribute__((address_space(3))) void*)(l), 16, 0, 0)

// ---------- fp32 -> fp16 with per-32 K-window permutation ------------------
__global__ void split_h(const float* __restrict__ A, u16* __restrict__ O,
                        int nblk, int Kd) {
  int b = blockIdx.x * 256 + threadIdx.x;
  if (b >= nblk) return;
  int perRow = Kd >> 3;
  int m = b / perRow, gb = b - m * perRow;
  int w = gb >> 2, g = gb & 3;
  const float* src = A + (size_t)m * Kd + (w << 5) + (g << 2);
  float4 v0 = *(const float4*)src;
  float4 v1 = *(const float4*)(src + 16);
  float e[8] = {v0.x, v0.y, v0.z, v0.w, v1.x, v1.y, v1.z, v1.w};
  ushort8 o;
#pragma unroll
  for (int j = 0; j < 8; ++j) o[j] = f16_rne(e[j]);
  *(ushort8*)(O + (size_t)b * 8) = o;
}

// ---------- transpose W[K][N] -> WT[N][K] fp16, K-permuted -----------------
__global__ __launch_bounds__(256) void transpose_h(
    const float* __restrict__ W, u16* __restrict__ Th, int Kd, int Nd) {
  __shared__ float t[32][33];
  int k0 = blockIdx.x * 32, n0 = blockIdx.y * 32;
  int i = threadIdx.x;
  {
    int kk = i >> 3, nn = (i & 7) << 2;
    float4 v = *(const float4*)&W[(size_t)(k0 + kk) * Nd + n0 + nn];
    t[kk][nn] = v.x; t[kk][nn + 1] = v.y; t[kk][nn + 2] = v.z; t[kk][nn + 3] = v.w;
  }
  __syncthreads();
  int n = i >> 3, t2 = i & 7;
  int g = t2 >> 1, h = t2 & 1;
  int kbase = h * 16 + g * 4;
  ushort4v o;
#pragma unroll
  for (int j = 0; j < 4; ++j) o[j] = f16_rne(t[kbase + j][n]);
  *(ushort4v*)(Th + (size_t)(n0 + n) * Kd + k0 + t2 * 4) = o;
}

// ---------- generic 64x64-tile fp32 fold GEMM ------------------------------
__global__ __launch_bounds__(256) void fold64(
    const float* __restrict__ A, int lda, int a_bx, int a_by,
    const float* __restrict__ B, int ldb, int b_bx, int b_by,
    float* __restrict__ C, int ldc, int c_bx, int c_by) {
  __shared__ float a_lds[64][132];
  __shared__ float b_lds[128][64];
  const int bx = blockIdx.x, by = blockIdx.y, tid = threadIdx.x;
  A += (size_t)bx * a_bx + (size_t)by * a_by;
  B += (size_t)bx * b_bx + (size_t)by * b_by;
  C += (size_t)bx * c_bx + (size_t)by * c_by;
  for (int i = tid; i < 64 * 32; i += 256) {
    int r = i >> 5, c4 = (i & 31) << 2;
    *(float4*)&a_lds[r][c4] = *(const float4*)&A[(size_t)r * lda + c4];
  }
  for (int i = tid; i < 128 * 16; i += 256) {
    int r = i >> 4, c4 = (i & 15) << 2;
    *(float4*)&b_lds[r][c4] = *(const float4*)&B[(size_t)r * ldb + c4];
  }
  __syncthreads();
  const int r = tid >> 2, l0 = (tid & 3) << 4;
  float acc[16] = {};
  for (int k = 0; k < 128; ++k) {
    float av = a_lds[r][k];
    const float* bp = &b_lds[k][l0];
#pragma unroll
    for (int j = 0; j < 16; ++j) acc[j] += av * bp[j];
  }
#pragma unroll
  for (int j4 = 0; j4 < 4; ++j4)
    *(float4*)&C[(size_t)r * ldc + l0 + j4 * 4] = *(float4*)&acc[j4 * 4];
}

// ---------- folded biases ---------------------------------------------------
__global__ void bias_prep(const float* __restrict__ bv, const float* __restrict__ Wcv,
                          const float* __restrict__ bcv, const float* __restrict__ bd,
                          const float* __restrict__ Wo, const float* __restrict__ bo,
                          float* __restrict__ bias_vf, float* __restrict__ bias_out) {
  int idx = blockIdx.x * 256 + threadIdx.x;
  if (idx < 1024) {
    int h = idx >> 6, l = idx & 63;
    float s = bcv[l];
    for (int j = 0; j < 128; ++j) s += bv[h * 128 + j] * Wcv[j * 64 + l];
    bias_vf[idx] = s;
  } else if (idx < 3072) {
    int n = idx - 1024;
    float s = bo[n];
    for (int k = 0; k < 2048; ++k) s += bd[k & 127] * Wo[(size_t)k * 2048 + n];
    bias_out[n] = s;
  }
}

// ---------- fused QKV GEMM fp16, 2-phase double-buffered -------------------
__global__ __launch_bounds__(256) void gemm_qkv(
    const u16* __restrict__ Af, const u16* __restrict__ Bf,
    float* __restrict__ cQ, float* __restrict__ cK, float* __restrict__ cV,
    const float* __restrict__ bq, const float* __restrict__ bk,
    const float* __restrict__ bvf, int K) {
  __shared__ u16 s[2][2][128 * 32];  // [buf][A/B], 32KB total
  const int tid = threadIdx.x;
  const int lane = tid & 63;
  const int w = tid >> 6, wr = w >> 1, wc = w & 1;
  const int row0 = blockIdx.y * 128, col0 = blockIdx.x * 128;

  const int sr = tid >> 2, sq = tid & 3;
  const int sg = sq ^ ((sr >> 1) & 3);
  const size_t aoff0 = (size_t)(row0 + sr) * K + sg * 8;
  const size_t aoff1 = (size_t)(row0 + sr + 64) * K + sg * 8;
  const size_t boff0 = (size_t)(col0 + sr) * K + sg * 8;
  const size_t boff1 = (size_t)(col0 + sr + 64) * K + sg * 8;
  const int ldst0 = tid * 16, ldst1 = (tid + 256) * 16;

  f32x4 acc[4][4];
#pragma unroll
  for (int i2 = 0; i2 < 4; ++i2)
#pragma unroll
    for (int j2 = 0; j2 < 4; ++j2) acc[i2][j2] = (f32x4){0.f, 0.f, 0.f, 0.f};

  int fa[4], fb[4];
#pragma unroll
  for (int mi = 0; mi < 4; ++mi) {
    int ra = wr * 64 + mi * 16 + (lane & 15);
    fa[mi] = ra * 64 + (((lane >> 4) ^ ((ra >> 1) & 3)) << 4);
    int rb = wc * 64 + mi * 16 + (lane & 15);
    fb[mi] = rb * 64 + (((lane >> 4) ^ ((rb >> 1) & 3)) << 4);
  }

  // prologue: stage tile 0 into buf 0
  GL(Af + aoff0, (char*)&s[0][0][0] + ldst0);
  GL(Af + aoff1, (char*)&s[0][0][0] + ldst1);
  GL(Bf + boff0, (char*)&s[0][1][0] + ldst0);
  GL(Bf + boff1, (char*)&s[0][1][0] + ldst1);
  int cur = 0;
  for (int k0 = 0; k0 < K; k0 += 32) {
    __syncthreads();  // implicit vmcnt(0): stage(cur) done; prev reads done
    if (k0 + 32 < K) {
      const int nb = cur ^ 1;
      GL(Af + aoff0 + k0 + 32, (char*)&s[nb][0][0] + ldst0);
      GL(Af + aoff1 + k0 + 32, (char*)&s[nb][0][0] + ldst1);
      GL(Bf + boff0 + k0 + 32, (char*)&s[nb][1][0] + ldst0);
      GL(Bf + boff1 + k0 + 32, (char*)&s[nb][1][0] + ldst1);
    }
    half8 a[4], b[4];
#pragma unroll
    for (int mi = 0; mi < 4; ++mi) {
      a[mi] = *(const half8*)((const char*)&s[cur][0][0] + fa[mi]);
      b[mi] = *(const half8*)((const char*)&s[cur][1][0] + fb[mi]);
    }
#pragma unroll
    for (int mi = 0; mi < 4; ++mi)
#pragma unroll
      for (int ni = 0; ni < 4; ++ni)
        acc[mi][ni] = __builtin_amdgcn_mfma_f32_16x16x32_f16(a[mi], b[ni], acc[mi][ni], 0, 0, 0);
    cur ^= 1;
  }
  float* Cp; const float* bp; int ldc, cl0;
  if (col0 < 2048)      { Cp = cQ; bp = bq;  ldc = 2048; cl0 = col0; }
  else if (col0 < 4096) { Cp = cK; bp = bk;  ldc = 2048; cl0 = col0 - 2048; }
  else                  { Cp = cV; bp = bvf; ldc = 1024; cl0 = col0 - 4096; }
#pragma unroll
  for (int ni = 0; ni < 4; ++ni) {
    int c = cl0 + wc * 64 + ni * 16 + (lane & 15);
    float bias = bp[c];
#pragma unroll
    for (int mi = 0; mi < 4; ++mi) {
      int rr = row0 + wr * 64 + mi * 16 + ((lane >> 4) << 2);
#pragma unroll
      for (int r = 0; r < 4; ++r)
        Cp[(size_t)(rr + r) * ldc + c] = acc[mi][ni][r] + bias;
    }
  }
}

// ---------- fp16 MFMA GEMM (final out-projection), 2-phase -----------------
__global__ __launch_bounds__(256) void gemm_f16(
    const u16* __restrict__ Af, const u16* __restrict__ Bf,
    const float* __restrict__ bias, float* __restrict__ C,
    int M, int N, int K) {
  __shared__ u16 s[2][2][128 * 32];
  const int tid = threadIdx.x;
  const int lane = tid & 63;
  const int w = tid >> 6, wr = w >> 1, wc = w & 1;
  const int row0 = blockIdx.y * 128, col0 = blockIdx.x * 128;

  const int sr = tid >> 2, sq = tid & 3;
  const int sg = sq ^ ((sr >> 1) & 3);
  const size_t aoff0 = (size_t)(row0 + sr) * K + sg * 8;
  const size_t aoff1 = (size_t)(row0 + sr + 64) * K + sg * 8;
  const size_t boff0 = (size_t)(col0 + sr) * K + sg * 8;
  const size_t boff1 = (size_t)(col0 + sr + 64) * K + sg * 8;
  const int ldst0 = tid * 16, ldst1 = (tid + 256) * 16;

  f32x4 acc[4][4];
#pragma unroll
  for (int i2 = 0; i2 < 4; ++i2)
#pragma unroll
    for (int j2 = 0; j2 < 4; ++j2) acc[i2][j2] = (f32x4){0.f, 0.f, 0.f, 0.f};

  int fa[4], fb[4];
#pragma unroll
  for (int mi = 0; mi < 4; ++mi) {
    int ra = wr * 64 + mi * 16 + (lane & 15);
    fa[mi] = ra * 64 + (((lane >> 4) ^ ((ra >> 1) & 3)) << 4);
    int rb = wc * 64 + mi * 16 + (lane & 15);
    fb[mi] = rb * 64 + (((lane >> 4) ^ ((rb >> 1) & 3)) << 4);
  }

  GL(Af + aoff0, (char*)&s[0][0][0] + ldst0);
  GL(Af + aoff1, (char*)&s[0][0][0] + ldst1);
  GL(Bf + boff0, (char*)&s[0][1][0] + ldst0);
  GL(Bf + boff1, (char*)&s[0][1][0] + ldst1);
  int cur = 0;
  for (int k0 = 0; k0 < K; k0 += 32) {
    __syncthreads();
    if (k0 + 32 < K) {
      const int nb = cur ^ 1;
      GL(Af + aoff0 + k0 + 32, (char*)&s[nb][0][0] + ldst0);
      GL(Af + aoff1 + k0 + 32, (char*)&s[nb][0][0] + ldst1);
      GL(Bf + boff0 + k0 + 32, (char*)&s[nb][1][0] + ldst0);
      GL(Bf + boff1 + k0 + 32, (char*)&s[nb][1][0] + ldst1);
    }
    half8 a[4], b[4];
#pragma unroll
    for (int mi = 0; mi < 4; ++mi) {
      a[mi] = *(const half8*)((const char*)&s[cur][0][0] + fa[mi]);
      b[mi] = *(const half8*)((const char*)&s[cur][1][0] + fb[mi]);
    }
#pragma unroll
    for (int mi = 0; mi < 4; ++mi)
#pragma unroll
      for (int ni = 0; ni < 4; ++ni)
        acc[mi][ni] = __builtin_amdgcn_mfma_f32_16x16x32_f16(a[mi], b[ni], acc[mi][ni], 0, 0, 0);
    cur ^= 1;
  }
#pragma unroll
  for (int ni = 0; ni < 4; ++ni) {
    int c = col0 + wc * 64 + ni * 16 + (lane & 15);
    float bv = bias[c];
#pragma unroll
    for (int mi = 0; mi < 4; ++mi) {
      int rr = row0 + wr * 64 + mi * 16 + ((lane >> 4) << 2);
#pragma unroll
      for (int r = 0; r < 4; ++r)
        C[(size_t)(rr + r) * N + c] = acc[mi][ni][r] + bv;
    }
  }
}

// ---------- fused RoPE + latent compression via fp16 MFMA ------------------
// grid (T/64, B*H). src fp32 [B*T][D]; WcT fp16 [64][128] K-perm;
// out dst [bh][T][64] bf16 lat-permuted.
__global__ __launch_bounds__(256) void compress_qk_mfma(
    const float* __restrict__ src, const u16* __restrict__ WcT,
    const float* __restrict__ bc, const float* __restrict__ freqs,
    u16* __restrict__ dst) {
  __shared__ u16 q_lds[64 * 128];  // 16KB, XOR-swizzled 16B slots
  __shared__ u16 w_lds[64 * 128];  // 16KB, XOR-swizzled (pre-swizzled source)
  const int tid = threadIdx.x;
  const int lane = tid & 63;
  const int w = tid >> 6;
  const int t0 = blockIdx.x * 64;
  const int bh = blockIdx.y, b = bh >> 4, h = bh & 15;

  // stage WcT: linear LDS dest, source pre-swizzled (rule #21)
#pragma unroll
  for (int j = 0; j < 4; ++j) {
    int idx = tid + j * 256;            // 16B chunk id 0..1023
    int row = idx >> 4, slot = idx & 15;
    GL(WcT + (size_t)row * 128 + (size_t)(slot ^ (row & 7)) * 8,
       (char*)w_lds + idx * 16);
  }
  // RoPE'd Q row -> fp16 -> swizzled LDS
  const int r = tid >> 2, seg = tid & 3;
  const float* qp = src + ((size_t)(b * Tn + t0 + r)) * Dn + h * 128 + seg * 32;
  const float* fp = freqs + (size_t)(t0 + r) * 64 + seg * 16;
  float fr[16];
#pragma unroll
  for (int j = 0; j < 4; ++j) *(float4*)&fr[4 * j] = ((const float4*)fp)[j];
#pragma unroll
  for (int j = 0; j < 8; ++j) {
    float4 v = ((const float4*)qp)[j];
    float s0, c0, s1, c1;
    sincosf(fr[2 * j], &s0, &c0);
    sincosf(fr[2 * j + 1], &s1, &c1);
    ushort4v u;
    u[0] = f16_rne(v.x * c0 - v.y * s0);
    u[1] = f16_rne(v.x * s0 + v.y * c0);
    u[2] = f16_rne(v.z * c1 - v.w * s1);
    u[3] = f16_rne(v.z * s1 + v.w * c1);
    // d = seg*32 + 4j..4j+3 -> perm slot g=j&3, half h=j>>2
    int slot = seg * 4 + (j & 3);
    *(ushort4v*)((char*)q_lds + r * 256 + ((slot ^ (r & 7)) << 4) + (j >> 2) * 8) = u;
  }
  __syncthreads();  // drains GL (vmcnt) and ds_writes (lgkm)
  const int l15 = lane & 15, lg = lane >> 4;
  const int arow = w * 16 + l15;
  half8 af[4];
#pragma unroll
  for (int ks = 0; ks < 4; ++ks)
    af[ks] = *(const half8*)((const char*)q_lds + arow * 256 +
                             (((ks * 4 + lg) ^ (arow & 7)) << 4));
  f32x4 acc[4];
#pragma unroll
  for (int ni = 0; ni < 4; ++ni) acc[ni] = (f32x4){0.f, 0.f, 0.f, 0.f};
#pragma unroll
  for (int ni = 0; ni < 4; ++ni) {
    const int brow = ni * 16 + l15;
#pragma unroll
    for (int ks = 0; ks < 4; ++ks) {
      half8 bf = *(const half8*)((const char*)w_lds + brow * 256 +
                                 (((ks * 4 + lg) ^ (brow & 7)) << 4));
      acc[ni] = __builtin_amdgcn_mfma_f32_16x16x32_f16(af[ks], bf, acc[ni], 0, 0, 0);
    }
  }
  __syncthreads();  // all q_lds reads done -> reuse as output staging
  // stage bf16 output [64 t][64 lat-perm] into q_lds (wave region w*1024)
#pragma unroll
  for (int ni = 0; ni < 4; ++ni) {
    int lat = ni * 16 + l15;
    float bcv = bc[lat];
    int p = (lat & 32) + ((lat >> 2) & 3) * 8 + ((lat >> 4) & 1) * 4 + (lat & 3);
#pragma unroll
    for (int reg = 0; reg < 4; ++reg)
      q_lds[w * 1024 + (lg * 4 + reg) * 64 + p] = bf_rne(acc[ni][reg] + bcv);
  }
  __syncthreads();
  // coalesced global write: 64 rows x 64 u16
#pragma unroll
  for (int j = 0; j < 2; ++j) {
    int idx = tid + j * 256;           // 16B chunk, 512 total
    int row = idx >> 3, c8 = idx & 7;
    ushort8 val = *(const ushort8*)&q_lds[row * 64 + c8 * 8];
    *(ushort8*)(dst + ((size_t)bh * Tn + t0 + row) * 64 + c8 * 8) = val;
  }
}

// ---------- transpose v_lat [B*T][1024] -> vlatT [bh][64][T-perm] bf16 -----
__global__ __launch_bounds__(256) void transpose_v(
    const float* __restrict__ vlat, u16* __restrict__ vlatT) {
  __shared__ u16 o_lds[64][64];
  const int tid = threadIdx.x;
  const int t0 = blockIdx.x * 64;
  const int bh = blockIdx.y, b = bh >> 4, h = bh & 15;
  const int tt = tid >> 2, lseg = tid & 3;
  const float* vp = vlat + (size_t)(b * Tn + t0 + tt) * 1024 + h * 64 + lseg * 16;
#pragma unroll
  for (int g = 0; g < 4; ++g) {
    float4 v = ((const float4*)vp)[g];
    ushort4v u = {bf_rne(v.x), bf_rne(v.y), bf_rne(v.z), bf_rne(v.w)};
    *(ushort4v*)&o_lds[tt][lseg * 16 + ((g ^ (tt & 3)) << 2)] = u;
  }
  __syncthreads();
  const int lat = tid >> 2, tseg = tid & 3;
  const int tw = tseg >> 1, h4 = tseg & 1;
  u16 vals[16];
#pragma unroll
  for (int i = 0; i < 16; ++i)
    vals[i] = o_lds[tseg * 16 + i][lat ^ ((i & 3) << 2)];
  u16* dp = vlatT + ((size_t)bh * 64 + lat) * Tn + t0 + tw * 32 + h4 * 4;
#pragma unroll
  for (int g = 0; g < 4; ++g) {
    ushort4v u = {vals[g * 4 + 0], vals[g * 4 + 1], vals[g * 4 + 2], vals[g * 4 + 3]};
    *(ushort4v*)(dp + g * 8) = u;
  }
}

// ---------- MFMA flash attention (latent dim 64, causal) -------------------
// T14 async-stage: issue next tile's global loads before current compute.
__global__ __launch_bounds__(256) void attn_mfma(
    const u16* __restrict__ qlat, const u16* __restrict__ klat,
    const u16* __restrict__ vlatT, float* __restrict__ olatT) {
  __shared__ u16 Ks[64 * 72];
  __shared__ u16 Vs[64 * 72];
  const int tid = threadIdx.x;
  const int lane = tid & 63;
  const int w = tid >> 6;
  const int bh = blockIdx.y;
  const int q0 = (int)(gridDim.x - 1 - blockIdx.x) * 128;
  const int qw = q0 + w * 32;
  const u16* ql = qlat + (size_t)bh * Tn * 64;
  const u16* kl = klat + (size_t)bh * Tn * 64;
  const u16* vt = vlatT + (size_t)bh * 64 * Tn;
  float* ot = olatT + (size_t)bh * 64 * Tn;
  const int l15 = lane & 15, lg = lane >> 4;

  short8 qf[2][2];
#pragma unroll
  for (int nf = 0; nf < 2; ++nf)
#pragma unroll
    for (int ks = 0; ks < 2; ++ks)
      qf[nf][ks] = *(const short8*)(ql + (size_t)(qw + nf * 16 + l15) * 64 + (ks * 4 + lg) * 8);

  f32x4 accO[4][2];
#pragma unroll
  for (int mi = 0; mi < 4; ++mi)
#pragma unroll
    for (int nf = 0; nf < 2; ++nf) accO[mi][nf] = (f32x4){0.f, 0.f, 0.f, 0.f};
  float mrow[2] = {-1e30f, -1e30f}, lrow[2] = {0.f, 0.f};

  const int srow = tid >> 2, spair = tid & 3;
  u16* ksw = &Ks[srow * 72 + spair * 16];
  u16* vsw = &Vs[srow * 72 + spair * 16];
  const u16* kgp = kl + (size_t)srow * 64 + spair * 16;
  const u16* vgp = vt + (size_t)srow * Tn + spair * 16;

  // prologue: load tile 0 into regs
  short8 kr0 = *(const short8*)(kgp);
  short8 kr1 = *(const short8*)(kgp + 8);
  short8 vr0 = *(const short8*)(vgp);
  short8 vr1 = *(const short8*)(vgp + 8);

  const int ntiles = q0 / 64 + 2;
  for (int kt = 0; kt < ntiles; ++kt) {
    const int k0 = kt * 64;
    __syncthreads();              // prev tile's LDS reads done
    *(short8*)ksw       = kr0;
    *(short8*)(ksw + 8) = kr1;
    *(short8*)vsw       = vr0;
    *(short8*)(vsw + 8) = vr1;
    __syncthreads();              // LDS visible
    {                             // issue next tile's loads (overlap compute)
      int kn = k0 + 64; kn = kn > (int)Tn - 64 ? (int)Tn - 64 : kn;
      kr0 = *(const short8*)(kgp + (size_t)kn * 64);
      kr1 = *(const short8*)(kgp + (size_t)kn * 64 + 8);
      vr0 = *(const short8*)(vgp + kn);
      vr1 = *(const short8*)(vgp + kn + 8);
    }
    if (k0 <= qw + 31) {
      f32x4 s4[4][2];
#pragma unroll
      for (int mi = 0; mi < 4; ++mi) {
        s4[mi][0] = (f32x4){0.f, 0.f, 0.f, 0.f};
        s4[mi][1] = (f32x4){0.f, 0.f, 0.f, 0.f};
      }
#pragma unroll
      for (int ks = 0; ks < 2; ++ks) {
        short8 kf[4];
#pragma unroll
        for (int mi = 0; mi < 4; ++mi)
          kf[mi] = *(const short8*)&Ks[(mi * 16 + l15) * 72 + (ks * 4 + lg) * 8];
#pragma unroll
        for (int mi = 0; mi < 4; ++mi) {
          s4[mi][0] = __builtin_amdgcn_mfma_f32_16x16x32_bf16(kf[mi], qf[0][ks], s4[mi][0], 0, 0, 0);
          s4[mi][1] = __builtin_amdgcn_mfma_f32_16x16x32_bf16(kf[mi], qf[1][ks], s4[mi][1], 0, 0, 0);
        }
      }
      short8 pf[2][2];
#pragma unroll
      for (int nf = 0; nf < 2; ++nf) {
        const int qidx = qw + nf * 16 + l15;
        float p[4][4];
        float tmax = -1e30f;
#pragma unroll
        for (int mi = 0; mi < 4; ++mi)
#pragma unroll
          for (int rr = 0; rr < 4; ++rr) {
            int kv = k0 + mi * 16 + lg * 4 + rr;
            float v = s4[mi][nf][rr] * SL2E;
            if (kv > qidx) v = -1e30f;
            p[mi][rr] = v;
            tmax = fmaxf(tmax, v);
          }
        tmax = fmaxf(tmax, __shfl_xor(tmax, 16));
        tmax = fmaxf(tmax, __shfl_xor(tmax, 32));
        float mnew = fmaxf(mrow[nf], tmax);
        float alpha = exp2f(mrow[nf] - mnew);
        mrow[nf] = mnew;
        float psum = 0.f;
#pragma unroll
        for (int mi = 0; mi < 4; ++mi)
#pragma unroll
          for (int rr = 0; rr < 4; ++rr) {
            float e = exp2f(p[mi][rr] - mnew);
            unsigned hb = __float_as_uint(e) & 0xffff0000u;
            psum += __uint_as_float(hb);
            p[mi][rr] = __uint_as_float(hb);
          }
        psum += __shfl_xor(psum, 16);
        psum += __shfl_xor(psum, 32);
        lrow[nf] = lrow[nf] * alpha + psum;
#pragma unroll
        for (int mi = 0; mi < 4; ++mi)
#pragma unroll
          for (int rr = 0; rr < 4; ++rr) accO[mi][nf][rr] *= alpha;
#pragma unroll
        for (int ks = 0; ks < 2; ++ks) {
          short8 f;
#pragma unroll
          for (int rr = 0; rr < 4; ++rr) {
            f[rr]     = (short)(__float_as_uint(p[2 * ks][rr]) >> 16);
            f[4 + rr] = (short)(__float_as_uint(p[2 * ks + 1][rr]) >> 16);
          }
          pf[nf][ks] = f;
        }
      }
#pragma unroll
      for (int ks = 0; ks < 2; ++ks) {
        short8 vf[4];
#pragma unroll
        for (int mi = 0; mi < 4; ++mi)
          vf[mi] = *(const short8*)&Vs[(mi * 16 + l15) * 72 + (ks * 4 + lg) * 8];
#pragma unroll
        for (int mi = 0; mi < 4; ++mi) {
          accO[mi][0] = __builtin_amdgcn_mfma_f32_16x16x32_bf16(vf[mi], pf[0][ks], accO[mi][0], 0, 0, 0);
          accO[mi][1] = __builtin_amdgcn_mfma_f32_16x16x32_bf16(vf[mi], pf[1][ks], accO[mi][1], 0, 0, 0);
        }
      }
    }
  }
#pragma unroll
  for (int nf = 0; nf < 2; ++nf) {
    float inv = 1.f / lrow[nf];
    int q = qw + nf * 16 + l15;
#pragma unroll
    for (int mi = 0; mi < 4; ++mi)
#pragma unroll
      for (int rr = 0; rr < 4; ++rr)
        ot[(size_t)(mi * 16 + lg * 4 + rr) * Tn + q] = accO[mi][nf][rr] * inv;
  }
}

// ---------- olatT [bh][64][T] fp32 -> oh [B*T][1024] fp16 K-permuted -------
__global__ __launch_bounds__(256) void o_split(
    const float* __restrict__ olatT, u16* __restrict__ oh) {
  __shared__ u16 hs[64][64];
  const int tid = threadIdx.x;
  const int q0 = blockIdx.x * 64;
  const int bh = blockIdx.y, b = bh >> 4, h = bh & 15;
  const int lat = tid >> 2, qseg = tid & 3;
  const float* op = olatT + ((size_t)bh * 64 + lat) * Tn + q0 + qseg * 16;
#pragma unroll
  for (int g = 0; g < 4; ++g) {
    float4 v = ((const float4*)op)[g];
    ushort4v u = {f16_rne(v.x), f16_rne(v.y), f16_rne(v.z), f16_rne(v.w)};
    *(ushort4v*)&hs[lat][qseg * 16 + ((g ^ (lat & 3)) << 2)] = u;
  }
  __syncthreads();
  const int qq = tid >> 2, lseg = tid & 3;
  u16 vh[16];
#pragma unroll
  for (int i = 0; i < 16; ++i)
    vh[i] = hs[lseg * 16 + i][qq ^ ((i & 3) << 2)];
  size_t rb = (size_t)(b * Tn + q0 + qq) * 1024 + h * 64 + (lseg >> 1) * 32 + (lseg & 1) * 4;
#pragma unroll
  for (int g = 0; g < 4; ++g) {
    ushort4v u = {vh[g * 4], vh[g * 4 + 1], vh[g * 4 + 2], vh[g * 4 + 3]};
    *(ushort4v*)(oh + rb + g * 8) = u;
  }
}

// ---------------------------------------------------------------------------
extern "C" void kernel_launch(void* const* d_in, const int* in_sizes, int n_in,
                              void* d_out, int out_size, void* d_ws, size_t ws_size,
                              hipStream_t stream) {
  const float* x     = (const float*)d_in[0];
  const float* freqs = (const float*)d_in[1];
  const float* Wq  = (const float*)d_in[3];  const float* bq  = (const float*)d_in[4];
  const float* Wk  = (const float*)d_in[5];  const float* bk  = (const float*)d_in[6];
  const float* Wv  = (const float*)d_in[7];  const float* bv  = (const float*)d_in[8];
  const float* Wo  = (const float*)d_in[9];  const float* bo  = (const float*)d_in[10];
  const float* Wcq = (const float*)d_in[11]; const float* bcq = (const float*)d_in[12];
  const float* Wck = (const float*)d_in[13]; const float* bck = (const float*)d_in[14];
  const float* Wcv = (const float*)d_in[15]; const float* bcv = (const float*)d_in[16];
  const float* Wd  = (const float*)d_in[17]; const float* bd  = (const float*)d_in[18];
  float* out = (float*)d_out;

  const size_t BT = (size_t)Bsz * Tn;          // 4096
  const size_t nQ = BT * Dn;                   // 8.39M
  const size_t nL = BT * Hn * Ln;              // 4.19M
  const size_t nWT = (size_t)5120 * 2048;      // 10.49M

  char* ws = (char*)d_ws;
  u16* xf   = (u16*)ws;                               // 16.8 MB
  u16* WTf  = xf + nQ;                                // 21.0 MB
  float* Wvf = (float*)(WTf + nWT);                   // 8.4 MB [2048][1024]
  float* Q    = Wvf + (size_t)2048 * 1024;            // 33.6 MB
  float* Kb   = Q + nQ;                               // 33.6 MB
  float* vlat = Kb + nQ;                              // 16.8 MB [4096][1024]
  float* bias_vf  = vlat + (size_t)4096 * 1024;       // 4 KB
  float* bias_out = bias_vf + 1024;                   // 8 KB
  u16* qlat  = (u16*)(bias_out + 2048);               // 8.4 MB
  u16* klat  = qlat + nL;                             // 8.4 MB
  u16* vlatT = klat + nL;                             // 8.4 MB
  float* olatT = (float*)(vlatT + nL);                // 16.8 MB
  u16* oh = (u16*)(olatT + nL);                       // 8.4 MB [4096][1024]
  float* Wdo = (float*)(oh + (size_t)4096 * 1024);    // 8.4 MB [1024][2048]
  u16* WdoT = (u16*)(Wdo + (size_t)1024 * 2048);      // 4.2 MB [2048][1024]
  u16* WcqT = WdoT + (size_t)2048 * 1024;             // 16 KB [64][128]
  u16* WckT = WcqT + (size_t)64 * 128;                // 16 KB

  dim3 blk(256);
  int nblkA = (int)(nQ / 8);

  // stage 1: operand prep
  split_h<<<(nblkA + 255) / 256, blk, 0, stream>>>(x, xf, nblkA, Dn);
  fold64<<<dim3(32, 16), blk, 0, stream>>>(Wv, 2048, 64 * 2048, 128,
                                           Wcv, 64, 0, 0,
                                           Wvf, 1024, 64 * 1024, 64);
  transpose_h<<<dim3(64, 64), blk, 0, stream>>>(Wq, WTf, 2048, 2048);
  transpose_h<<<dim3(64, 64), blk, 0, stream>>>(Wk, WTf + (size_t)2048 * 2048, 2048, 2048);
  transpose_h<<<dim3(64, 32), blk, 0, stream>>>(Wvf, WTf + (size_t)4096 * 2048, 2048, 1024);
  transpose_h<<<dim3(4, 2), blk, 0, stream>>>(Wcq, WcqT, 128, 64);
  transpose_h<<<dim3(4, 2), blk, 0, stream>>>(Wck, WckT, 128, 64);
  bias_prep<<<12, blk, 0, stream>>>(bv, Wcv, bcv, bd, Wo, bo, bias_vf, bias_out);

  // stage 2: fused Q/K/V-latent GEMM (N = 5120, fp16 MFMA, 2-phase)
  gemm_qkv<<<dim3(40, 32), blk, 0, stream>>>(xf, WTf, Q, Kb, vlat,
                                             bq, bk, bias_vf, 2048);

  // stage 3: latent Q/K (RoPE fused, MFMA) + V transpose
  dim3 gc(Tn / 64, Bsz * Hn);
  compress_qk_mfma<<<gc, blk, 0, stream>>>(Q,  WcqT, bcq, freqs, qlat);
  compress_qk_mfma<<<gc, blk, 0, stream>>>(Kb, WckT, bck, freqs, klat);
  transpose_v<<<gc, blk, 0, stream>>>(vlat, vlatT);

  // stage 4: attention
  attn_mfma<<<dim3(Tn / 128, Bsz * Hn), blk, 0, stream>>>(qlat, klat, vlatT, olatT);

  // stage 5: folded decompress+output projection (fp16 MFMA, 2-phase)
  o_split<<<gc, blk, 0, stream>>>(olatT, oh);
  fold64<<<dim3(32, 16), blk, 0, stream>>>(Wd, 128, 0, 0,
                                           Wo, 2048, 64, 128 * 2048,
                                           Wdo, 2048, 64, 64 * 2048);
  transpose_h<<<dim3(32, 64), blk, 0, stream>>>(Wdo, WdoT, 1024, 2048);
  gemm_f16<<<dim3(16, 32), blk, 0, stream>>>(oh, WdoT, bias_out, out, (int)BT, 2048, 1024);
}